// Round 2
// baseline (529.029 us; speedup 1.0000x reference)
//
#include <hip/hip_runtime.h>
#include <math.h>

#define B_ 4
#define N_ 4096
#define C_ 1024
#define H_ 16
#define D_ 64
#define M_ (B_*N_)      // 16384 rows
#define GK 1024         // GEMM K dim (both GEMMs)
#define NCH 8           // N-chunks for kv partial reduction
#define CHROWS (N_/NCH) // 512

typedef __attribute__((ext_vector_type(8))) _Float16 f16x8;
typedef __attribute__((ext_vector_type(4))) _Float16 f16x4;
typedef __attribute__((ext_vector_type(4))) float f32x4;

__device__ __forceinline__ float phi_f(float t) {
  return (t > 0.0f) ? (t + 1.0f) : __expf(t);
}

#define GLOAD(gp, lp) __builtin_amdgcn_global_load_lds( \
    (const __attribute__((address_space(1))) unsigned int*)(gp), \
    (__attribute__((address_space(3))) unsigned int*)(lp), 16, 0, 0)

#define BAR() __builtin_amdgcn_s_barrier()
#define SCHEDB() __builtin_amdgcn_sched_barrier(0)
#define WAITV6() asm volatile("s_waitcnt vmcnt(6)" ::: "memory")
#define WAITV0() asm volatile("s_waitcnt vmcnt(0)" ::: "memory")
#define PRIO1() __builtin_amdgcn_s_setprio(1)
#define PRIO0() __builtin_amdgcn_s_setprio(0)

__device__ __forceinline__ f32x4 mfma16h(f16x8 a, f16x8 b, f32x4 c) {
  return __builtin_amdgcn_mfma_f32_16x16x32_f16(a, b, c, 0, 0, 0);
}

// ---------------- mask dtype detection ----------------
__global__ __launch_bounds__(256) void mask_detect_k(const unsigned int* __restrict__ w,
                                                     int* __restrict__ flag) {
  __shared__ int notint, notflt;
  if (threadIdx.x == 0) { notint = 0; notflt = 0; }
  __syncthreads();
  int ni = 0, nf = 0;
  for (int i = threadIdx.x; i < 4096; i += 256) {
    unsigned int v = w[i];
    if (v > 1u) ni = 1;
    if (v != 0u && v != 0x3F800000u) nf = 1;
  }
  if (ni) atomicOr(&notint, 1);
  if (nf) atomicOr(&notflt, 1);
  __syncthreads();
  if (threadIdx.x == 0) *flag = (!notint) ? 0 : ((!notflt) ? 1 : 2);
}

__global__ __launch_bounds__(256) void mask_convert_k(const void* __restrict__ mask,
                                                      const int* __restrict__ flag,
                                                      float* __restrict__ valid) {
  int i = blockIdx.x * 256 + threadIdx.x;  // 16384 total
  int f = *flag;
  int m;
  if (f == 0)      m = ((const int*)mask)[i] != 0;
  else if (f == 1) m = ((const float*)mask)[i] != 0.0f;
  else             m = ((const unsigned char*)mask)[i] != 0;
  valid[i] = m ? 0.0f : 1.0f;  // True = PAD -> 0
}

// ---------------- fp32 -> fp16 single convert (x4) ----------------
__global__ __launch_bounds__(256) void conv_f16_k(const float* __restrict__ src,
                                                  _Float16* __restrict__ dst, int n4) {
  int i = blockIdx.x * 256 + threadIdx.x;
  if (i >= n4) return;
  float4 v = ((const float4*)src)[i];
  f16x4 h;
  h[0] = (_Float16)v.x; h[1] = (_Float16)v.y;
  h[2] = (_Float16)v.z; h[3] = (_Float16)v.w;
  ((f16x4*)dst)[i] = h;
}

// ---------------- fp32 -> fp16 hi/lo split (x4) ----------------
__global__ __launch_bounds__(256) void split_f16_k(const float* __restrict__ src,
                                                   _Float16* __restrict__ h,
                                                   _Float16* __restrict__ l, int n4) {
  int i = blockIdx.x * 256 + threadIdx.x;
  if (i >= n4) return;
  float4 v = ((const float4*)src)[i];
  f16x4 hv, lv;
  float vs[4] = {v.x, v.y, v.z, v.w};
#pragma unroll
  for (int q = 0; q < 4; ++q) {
    _Float16 hh = (_Float16)vs[q];
    _Float16 ll = (_Float16)(vs[q] - (float)hh);
    hv[q] = hh; lv[q] = ll;
  }
  ((f16x4*)h)[i] = hv;
  ((f16x4*)l)[i] = lv;
}

// ---------------- 2-term fp16 MFMA GEMM, 256x256 tile, pipelined schedule ----------------
// out[m][j] = sum_k A[m][k] * (Bh[j][k] + Bl[j][k])
// 8 waves (2M x 4N), per-wave 128x64 output, K-tile = 32, 3-deep LDS buffers.
// ONE barrier per K-tile; fragment ds_reads software-pipelined one phase ahead
// (compiler inserts counted lgkmcnt, so reads overlap the previous MFMA
// cluster); GLOADs for tile t+2 issued after the mid-tile barrier (so no
// end-of-tile barrier is needed for buffer-overwrite safety); accumulation
// order per acc unchanged from r1 (bit-identical numerics).
// EPI 0: qkv epilogue (bias + phi/mask -> [B,H,N,D] fp32); EPI 1: bias + row-major fp32.
template <int EPI>
__global__ __launch_bounds__(512, 2) void gemm256_k(
    const _Float16* __restrict__ A,
    const _Float16* __restrict__ Bh, const _Float16* __restrict__ Bl,
    const float* __restrict__ bias, const float* __restrict__ valid,
    float* __restrict__ qf, float* __restrict__ kf, float* __restrict__ vv,
    float* __restrict__ outp, int jb, int jshift) {
  // per K-tile buffer: A 256x32 (8192 halfs) + Bh 8192 + Bl 8192 = 48 KiB; x3 = 144 KiB
  __shared__ _Float16 lds[73728];
  const int tid = threadIdx.x;
  const int lane = tid & 63, w = tid >> 6;
  const int lm = lane & 15, lq = lane >> 4;
  const int wm = w >> 2, wj = w & 3;

  // XCD swizzle (bijective: nwg is a multiple of 8 here: 512/256/256)
  const int nwg = gridDim.x;
  const int q8 = nwg >> 3;
  const int wid = (blockIdx.x & 7) * q8 + (blockIdx.x >> 3);
  const int j_blk = wid & ((1 << jshift) - 1);
  const int m_blk = wid >> jshift;
  const int m0 = m_blk * 256;
  const int jg0 = jb + j_blk * 256;

  // per-lane global source offsets (halfs); frag f = r*8 + w covers rows f*16+lm
  const size_t gA0 = (size_t)(m0 + w * 16 + lm) * GK + lq * 8;
  const size_t gA1 = gA0 + (size_t)128 * GK;
  const size_t gB0 = (size_t)(jg0 + w * 16 + lm) * GK + lq * 8;
  const size_t gB1 = gB0 + (size_t)128 * GK;

  // ---- prologue: stage tiles 0 (buf0) and 1 (buf1), wait tile0 only ----
#pragma unroll
  for (int tt = 0; tt < 2; ++tt) {
    _Float16* sq = lds + tt * 24576;
    const size_t ks = (size_t)tt * 32;
    GLOAD(A + gA0 + ks, sq + w * 512);
    GLOAD(A + gA1 + ks, sq + 4096 + w * 512);
    GLOAD(Bh + gB0 + ks, sq + 8192 + w * 512);
    GLOAD(Bh + gB1 + ks, sq + 12288 + w * 512);
    GLOAD(Bl + gB0 + ks, sq + 16384 + w * 512);
    GLOAD(Bl + gB1 + ks, sq + 20480 + w * 512);
  }
  WAITV6();
  BAR();
  SCHEDB();

  f32x4 acc[8][4] = {};
  f16x8 a0[4], a1[4], bh[4], bl[4];
  // pre-read tile0's a0 + bh fragments
#pragma unroll
  for (int i = 0; i < 4; ++i)
    a0[i] = *(const f16x8*)&lds[(wm * 8 + i) * 512 + lane * 8];
#pragma unroll
  for (int j = 0; j < 4; ++j)
    bh[j] = *(const f16x8*)&lds[8192 + (wj * 4 + j) * 512 + lane * 8];

  int pc = 0;
  for (int t = 0; t < 32; ++t) {
    const _Float16* bb = lds + pc * 24576;
    const int pn = (pc == 2) ? 0 : pc + 1;
    const _Float16* nb = lds + pn * 24576;
    const int psl = (pc == 0) ? 2 : pc - 1;   // (t+2)%3
    _Float16* sq = lds + psl * 24576;
    const bool st = (t + 2 < 32);
    const size_t ks = (size_t)(t + 2) * 32;

    // ---- P1: read a1 (this tile); MFMA a0*bh ----
#pragma unroll
    for (int i = 0; i < 4; ++i)
      a1[i] = *(const f16x8*)&bb[(wm * 8 + 4 + i) * 512 + lane * 8];
    PRIO1();
#pragma unroll
    for (int i = 0; i < 4; ++i)
#pragma unroll
      for (int j = 0; j < 4; ++j)
        acc[i][j] = mfma16h(a0[i], bh[j], acc[i][j]);
    PRIO0();

    // ---- P2: read bl (this tile); MFMA a1*bh ----
#pragma unroll
    for (int j = 0; j < 4; ++j)
      bl[j] = *(const f16x8*)&bb[16384 + (wj * 4 + j) * 512 + lane * 8];
    PRIO1();
#pragma unroll
    for (int i = 0; i < 4; ++i)
#pragma unroll
      for (int j = 0; j < 4; ++j)
        acc[4 + i][j] = mfma16h(a1[i], bh[j], acc[4 + i][j]);
    PRIO0();

    // ---- the ONE barrier per tile: buffer pn (tile t+1) staged & visible ----
    WAITV0();
    BAR();
    SCHEDB();

    // ---- P3: preread next tile's a0; issue 3 stages (tile t+2); MFMA a0*bl ----
    f16x8 a0n[4], bhn[4];
    if (t < 31) {
#pragma unroll
      for (int i = 0; i < 4; ++i)
        a0n[i] = *(const f16x8*)&nb[(wm * 8 + i) * 512 + lane * 8];
    }
    if (st) {
      GLOAD(A + gA0 + ks, sq + w * 512);
      GLOAD(A + gA1 + ks, sq + 4096 + w * 512);
      GLOAD(Bh + gB0 + ks, sq + 8192 + w * 512);
    }
    PRIO1();
#pragma unroll
    for (int i = 0; i < 4; ++i)
#pragma unroll
      for (int j = 0; j < 4; ++j)
        acc[i][j] = mfma16h(a0[i], bl[j], acc[i][j]);
    PRIO0();

    // ---- P4: preread next tile's bh; issue 3 stages; MFMA a1*bl ----
    if (t < 31) {
#pragma unroll
      for (int j = 0; j < 4; ++j)
        bhn[j] = *(const f16x8*)&nb[8192 + (wj * 4 + j) * 512 + lane * 8];
    }
    if (st) {
      GLOAD(Bh + gB1 + ks, sq + 12288 + w * 512);
      GLOAD(Bl + gB0 + ks, sq + 16384 + w * 512);
      GLOAD(Bl + gB1 + ks, sq + 20480 + w * 512);
    }
    PRIO1();
#pragma unroll
    for (int i = 0; i < 4; ++i)
#pragma unroll
      for (int j = 0; j < 4; ++j)
        acc[4 + i][j] = mfma16h(a1[i], bl[j], acc[4 + i][j]);
    PRIO0();

    if (t < 31) {
#pragma unroll
      for (int i = 0; i < 4; ++i) { a0[i] = a0n[i]; bh[i] = bhn[i]; }
    }
    pc = pn;
  }

  // C/D layout: col = lane&15, row = (lane>>4)*4 + reg   [m89-verified]
  if (EPI == 0) {
    const int ty = jg0 >> 10;  // 0:q 1:k 2:v  (uniform per block: 256 | 1024)
    float* dst = (ty == 0) ? qf : ((ty == 1) ? kf : vv);
    float vld[8][4];
#pragma unroll
    for (int i = 0; i < 8; ++i)
#pragma unroll
      for (int r = 0; r < 4; ++r)
        vld[i][r] = (ty == 0) ? 1.0f : valid[m0 + wm * 128 + i * 16 + lq * 4 + r];
#pragma unroll
    for (int jt = 0; jt < 4; ++jt) {
      int jcol = jg0 + wj * 64 + jt * 16 + lm;
      float bj = bias[jcol];
      int c = jcol & 1023, hd = c >> 6, d = c & 63;
#pragma unroll
      for (int i = 0; i < 8; ++i)
#pragma unroll
        for (int r = 0; r < 4; ++r) {
          int m = m0 + wm * 128 + i * 16 + lq * 4 + r;
          int b = m >> 12, n = m & 4095;
          float val = acc[i][jt][r] + bj;
          if (ty <= 1) val = phi_f(val);
          if (ty >= 1) val *= vld[i][r];
          dst[(((size_t)(b * H_ + hd) * N_ + n) << 6) + d] = val;
        }
    }
  } else {
#pragma unroll
    for (int jt = 0; jt < 4; ++jt) {
      int jcol = jg0 + wj * 64 + jt * 16 + lm;
      float bj = bias[jcol];
#pragma unroll
      for (int i = 0; i < 8; ++i)
#pragma unroll
        for (int r = 0; r < 4; ++r) {
          int m = m0 + wm * 128 + i * 16 + lq * 4 + r;
          outp[(size_t)m * C_ + jcol] = acc[i][jt][r] + bj;
        }
    }
  }
}

// ---------------- kv partials: kv[bh][d][e] = sum_n kf[bh][n][d]*v[bh][n][e]; z[bh][d] ----------------
__global__ __launch_bounds__(256) void kv_partial_k(
    const float* __restrict__ kf, const float* __restrict__ vv,
    float* __restrict__ kvp, float* __restrict__ zp) {
  const int bh = blockIdx.x, ch = blockIdx.y;
  const float* kfr = kf + ((size_t)bh * N_ + ch * CHROWS) * 64;
  const float* vr  = vv + ((size_t)bh * N_ + ch * CHROWS) * 64;
  __shared__ float ks[8][64], vs[8][64];
  const int tid = threadIdx.x;
  const int d0 = tid >> 2, eg = tid & 3;
  float acc[16] = {};
  float zacc = 0.f;
  for (int nb = 0; nb < CHROWS; nb += 8) {
    {
      int which = tid >> 7;
      int fl = tid & 127;
      int rr = fl >> 4, cc = (fl & 15) * 4;
      const float* src = which ? vr : kfr;
      float4 t4 = *(const float4*)&src[(size_t)(nb + rr) * 64 + cc];
      float* d = which ? &vs[rr][cc] : &ks[rr][cc];
      *(float4*)d = t4;
    }
    __syncthreads();
#pragma unroll
    for (int r = 0; r < 8; ++r) {
      float kd = ks[r][d0];
      if (eg == 0) zacc += kd;
#pragma unroll
      for (int i = 0; i < 16; ++i) acc[i] += kd * vs[r][eg * 16 + i];
    }
    __syncthreads();
  }
  size_t base = ((size_t)bh * NCH + ch) * 4096 + (size_t)d0 * 64 + eg * 16;
#pragma unroll
  for (int i = 0; i < 16; i += 4)
    *(float4*)&kvp[base + i] = make_float4(acc[i], acc[i+1], acc[i+2], acc[i+3]);
  if (eg == 0) zp[((size_t)bh * NCH + ch) * 64 + d0] = zacc;
}

__global__ __launch_bounds__(256) void kv_reduce_k(
    const float* __restrict__ kvp, const float* __restrict__ zp,
    float* __restrict__ kv, float* __restrict__ z) {
  const int bh = blockIdx.x, tid = threadIdx.x;
  for (int i = tid; i < 4096; i += 256) {
    float s = 0.f;
#pragma unroll
    for (int c = 0; c < NCH; ++c) s += kvp[((size_t)bh * NCH + c) * 4096 + i];
    kv[(size_t)bh * 4096 + i] = s;
  }
  if (tid < 64) {
    float s = 0.f;
#pragma unroll
    for (int c = 0; c < NCH; ++c) s += zp[((size_t)bh * NCH + c) * 64 + tid];
    z[bh * 64 + tid] = s;
  }
}

// ---------------- apply: Y[b,n,h*64+e] = (qf . kv) / max(qf . z, eps), fp16 out ----------------
__global__ __launch_bounds__(256) void attn_apply_k(
    const float* __restrict__ qf, const float* __restrict__ kv,
    const float* __restrict__ z, _Float16* __restrict__ Y) {
  const int bh = blockIdx.x, nt = blockIdx.y;
  const int b = bh >> 4, hd = bh & 15;
  __shared__ float qs[128][65];
  __shared__ float kvs[64][68];
  __shared__ float zs[64];
  __shared__ float dens[128];
  const int tid = threadIdx.x;
  const float* qrow = qf + ((size_t)bh * N_ + nt * 128) * 64;
#pragma unroll
  for (int i = 0; i < 4; ++i) {
    int fl = tid + i * 256;
    int d = fl >> 4, cc = (fl & 15) * 4;
    float4 t4 = *(const float4*)&kv[(size_t)bh * 4096 + d * 64 + cc];
    kvs[d][cc] = t4.x; kvs[d][cc+1] = t4.y; kvs[d][cc+2] = t4.z; kvs[d][cc+3] = t4.w;
  }
  if (tid < 64) zs[tid] = z[bh * 64 + tid];
#pragma unroll
  for (int i = 0; i < 8; ++i) {
    int fl = tid + i * 256;
    int r = fl >> 4, cc = (fl & 15) * 4;
    float4 t4 = *(const float4*)&qrow[(size_t)r * 64 + cc];
    qs[r][cc] = t4.x; qs[r][cc+1] = t4.y; qs[r][cc+2] = t4.z; qs[r][cc+3] = t4.w;
  }
  __syncthreads();
  {
    int n = tid >> 1, half = tid & 1;
    float s = 0.f;
#pragma unroll
    for (int dd = 0; dd < 32; ++dd) {
      int d = half * 32 + dd;
      s += qs[n][d] * zs[d];
    }
    float other = __shfl_down(s, 1);
    if (half == 0) dens[n] = fmaxf(s + other, 1e-6f);
  }
  __syncthreads();
  const int ng = tid >> 3, eg = tid & 7;
  float acc[4][8] = {};
  for (int d = 0; d < 64; ++d) {
    float kvrow[8];
    *(float4*)&kvrow[0] = *(const float4*)&kvs[d][eg * 8];
    *(float4*)&kvrow[4] = *(const float4*)&kvs[d][eg * 8 + 4];
#pragma unroll
    for (int i = 0; i < 4; ++i) {
      float a = qs[ng * 4 + i][d];
#pragma unroll
      for (int j = 0; j < 8; ++j) acc[i][j] += a * kvrow[j];
    }
  }
#pragma unroll
  for (int i = 0; i < 4; ++i) {
    int nl = ng * 4 + i;
    int n = nt * 128 + nl;
    float inv = 1.0f / dens[nl];
    size_t off = ((size_t)b * N_ + n) * C_ + hd * 64 + eg * 8;
    f16x8 hv;
#pragma unroll
    for (int j = 0; j < 8; ++j) hv[j] = (_Float16)(acc[i][j] * inv);
    *(f16x8*)&Y[off] = hv;
  }
}

extern "C" void kernel_launch(void* const* d_in, const int* in_sizes, int n_in,
                              void* d_out, int out_size, void* d_ws, size_t ws_size,
                              hipStream_t stream) {
  const float* x      = (const float*)d_in[0];
  const float* W_qkv  = (const float*)d_in[1];
  const float* b_qkv  = (const float*)d_in[2];
  const float* W_out  = (const float*)d_in[3];
  const float* b_out  = (const float*)d_in[4];
  const void*  mask   = d_in[5];
  float* out = (float*)d_out;

  const size_t bhnd = (size_t)B_ * H_ * N_ * D_;   // 16,777,216
  float* ws = (float*)d_ws;
  float* buf1 = ws;                    // kf, then qf (fp32)
  float* buf2 = ws + bhnd;             // v (fp32), then Y (fp16)
  _Float16* Xh  = (_Float16*)(ws + 2 * bhnd);      // bhnd halfs
  _Float16* Wqh = Xh + bhnd;                       // 3072*1024
  _Float16* Wql = Wqh + (size_t)3072 * 1024;
  _Float16* Woh = Wql + (size_t)3072 * 1024;       // 1024*1024
  _Float16* Wol = Woh + (size_t)1024 * 1024;
  float* tail2 = (float*)(Wol + (size_t)1024 * 1024);
  float* kvp = tail2;                              // 64*8*4096
  float* zp  = kvp + (size_t)64 * NCH * 4096;
  float* kv  = zp + (size_t)64 * NCH * 64;
  float* z   = kv + (size_t)64 * 4096;
  float* valid = z + 64 * 64;
  int*   flag  = (int*)(valid + M_);

  _Float16* Y = (_Float16*)buf2;

  mask_detect_k<<<1, 256, 0, stream>>>((const unsigned int*)mask, flag);
  mask_convert_k<<<M_ / 256, 256, 0, stream>>>(mask, flag, valid);
  conv_f16_k<<<(int)(bhnd / 4 / 256), 256, 0, stream>>>(x, Xh, (int)(bhnd / 4));
  split_f16_k<<<3072 * 1024 / 4 / 256, 256, 0, stream>>>(W_qkv, Wqh, Wql, 3072 * 1024 / 4);
  split_f16_k<<<1024 * 1024 / 4 / 256, 256, 0, stream>>>(W_out, Woh, Wol, 1024 * 1024 / 4);
  // phase A: K and V projections (j in [1024,3072)) -> kf(buf1), v(buf2)
  // grid = 64 m-blocks x 8 j-blocks = 512 (1D, swizzled in-kernel)
  gemm256_k<0><<<512, 512, 0, stream>>>(
      Xh, Wqh, Wql, b_qkv, valid, buf1, buf1, buf2, nullptr, 1024, 3);
  kv_partial_k<<<dim3(B_ * H_, NCH), 256, 0, stream>>>(buf1, buf2, kvp, zp);
  kv_reduce_k<<<B_ * H_, 256, 0, stream>>>(kvp, zp, kv, z);
  // phase B: Q projection (j in [0,1024)) -> qf into buf1 (kf dead)
  gemm256_k<0><<<256, 512, 0, stream>>>(
      Xh, Wqh, Wql, b_qkv, valid, buf1, buf1, buf2, nullptr, 0, 2);
  // apply: reads qf(buf1), writes Y (fp16) into buf2 (v dead)
  attn_apply_k<<<dim3(B_ * H_, N_ / 128), 256, 0, stream>>>(buf1, kv, z, Y);
  // out-proj: A = Y (fp16 single), B = W_out split-2
  gemm256_k<1><<<256, 512, 0, stream>>>(
      Y, Woh, Wol, b_out, valid, nullptr, nullptr, nullptr, out, 0, 2);
}

// Round 3
// 493.764 us; speedup vs baseline: 1.0714x; 1.0714x over previous
//
#include <hip/hip_runtime.h>
#include <math.h>

#define B_ 4
#define N_ 4096
#define C_ 1024
#define H_ 16
#define D_ 64
#define M_ (B_*N_)      // 16384 rows
#define GK 1024         // GEMM K dim (both GEMMs)
#define NCH 8           // N-chunks for kv partial reduction
#define CHROWS (N_/NCH) // 512

typedef __attribute__((ext_vector_type(8))) _Float16 f16x8;
typedef __attribute__((ext_vector_type(4))) _Float16 f16x4;
typedef __attribute__((ext_vector_type(4))) float f32x4;

__device__ __forceinline__ float phi_f(float t) {
  return (t > 0.0f) ? (t + 1.0f) : __expf(t);
}

#define GLOAD(gp, lp) __builtin_amdgcn_global_load_lds( \
    (const __attribute__((address_space(1))) unsigned int*)(gp), \
    (__attribute__((address_space(3))) unsigned int*)(lp), 16, 0, 0)

#define BARM() asm volatile("s_barrier" ::: "memory")
#define WAITV6() asm volatile("s_waitcnt vmcnt(6)" ::: "memory")
#define WAITV4() asm volatile("s_waitcnt vmcnt(4)" ::: "memory")
#define WAITV0() asm volatile("s_waitcnt vmcnt(0)" ::: "memory")
#define PRIO1() __builtin_amdgcn_s_setprio(1)
#define PRIO0() __builtin_amdgcn_s_setprio(0)

__device__ __forceinline__ f32x4 mfma16h(f16x8 a, f16x8 b, f32x4 c) {
  return __builtin_amdgcn_mfma_f32_16x16x32_f16(a, b, c, 0, 0, 0);
}

// ---------------- mask dtype detection ----------------
__global__ __launch_bounds__(256) void mask_detect_k(const unsigned int* __restrict__ w,
                                                     int* __restrict__ flag) {
  __shared__ int notint, notflt;
  if (threadIdx.x == 0) { notint = 0; notflt = 0; }
  __syncthreads();
  int ni = 0, nf = 0;
  for (int i = threadIdx.x; i < 4096; i += 256) {
    unsigned int v = w[i];
    if (v > 1u) ni = 1;
    if (v != 0u && v != 0x3F800000u) nf = 1;
  }
  if (ni) atomicOr(&notint, 1);
  if (nf) atomicOr(&notflt, 1);
  __syncthreads();
  if (threadIdx.x == 0) *flag = (!notint) ? 0 : ((!notflt) ? 1 : 2);
}

__global__ __launch_bounds__(256) void mask_convert_k(const void* __restrict__ mask,
                                                      const int* __restrict__ flag,
                                                      float* __restrict__ valid) {
  int i = blockIdx.x * 256 + threadIdx.x;  // 16384 total
  int f = *flag;
  int m;
  if (f == 0)      m = ((const int*)mask)[i] != 0;
  else if (f == 1) m = ((const float*)mask)[i] != 0.0f;
  else             m = ((const unsigned char*)mask)[i] != 0;
  valid[i] = m ? 0.0f : 1.0f;  // True = PAD -> 0
}

// ---------------- fp32 -> fp16 single convert (x4) ----------------
__global__ __launch_bounds__(256) void conv_f16_k(const float* __restrict__ src,
                                                  _Float16* __restrict__ dst, int n4) {
  int i = blockIdx.x * 256 + threadIdx.x;
  if (i >= n4) return;
  float4 v = ((const float4*)src)[i];
  f16x4 h;
  h[0] = (_Float16)v.x; h[1] = (_Float16)v.y;
  h[2] = (_Float16)v.z; h[3] = (_Float16)v.w;
  ((f16x4*)dst)[i] = h;
}

// ---------------- fp32 -> fp16 hi/lo split (x4) ----------------
__global__ __launch_bounds__(256) void split_f16_k(const float* __restrict__ src,
                                                   _Float16* __restrict__ h,
                                                   _Float16* __restrict__ l, int n4) {
  int i = blockIdx.x * 256 + threadIdx.x;
  if (i >= n4) return;
  float4 v = ((const float4*)src)[i];
  f16x4 hv, lv;
  float vs[4] = {v.x, v.y, v.z, v.w};
#pragma unroll
  for (int q = 0; q < 4; ++q) {
    _Float16 hh = (_Float16)vs[q];
    _Float16 ll = (_Float16)(vs[q] - (float)hh);
    hv[q] = hh; lv[q] = ll;
  }
  ((f16x4*)h)[i] = hv;
  ((f16x4*)l)[i] = lv;
}

// ---------------- 2-term fp16 MFMA GEMM, 256x256 tile, balanced 4-phase ----------------
// out[m][j] = sum_k A[m][k] * (Bh[j][k] + Bl[j][k])
// 8 waves (2M x 4N), per-wave 128x64, K-tile 32, 3-deep LDS (144 KiB, static
// buffer indices via 10x3 unroll).  Per phase: 4 ds_reads (operands for the
// NEXT phase's MFMA -> compiler-counted lgkmcnt overlaps reads with MFMA),
// 2 global_load_lds, 1 barrier, 16 MFMA wrapped in setprio.  vmcnt(4) at P2
// proves tile t+1 is staged before P3/P4 preread it.  Accumulation order per
// acc unchanged from r1 (bit-identical numerics).
// EPI 0: qkv epilogue (bias + phi/mask -> [B,H,N,D] fp32); EPI 1: bias + row-major fp32.

// One K-tile.  PC: static buffer index; DO_STAGE/DO_PRE compile-time;
// WAITK: 1 = vmcnt(4) (steady state), 2 = vmcnt(0) (t=30), 0 = none (t=31).
#define TILE_BODY(PC, DO_STAGE, DO_PRE, WAITK, KS)                             \
  {                                                                            \
    const _Float16* bb = lds + (PC) * 24576;                                   \
    const _Float16* nb = lds + (((PC) + 1) % 3) * 24576;                       \
    _Float16* sq = lds + (((PC) + 2) % 3) * 24576;                             \
    const size_t ks = (KS);                                                    \
    /* P1: read bl(cur); stage A; mma a0*bh */                                 \
    _Pragma("unroll") for (int j = 0; j < 4; ++j)                              \
      bl[j] = *(const f16x8*)&bb[16384 + (wj * 4 + j) * 512 + lane * 8];       \
    if (DO_STAGE) { GLOAD(A + gA0 + ks, sq + w * 512);                         \
                    GLOAD(A + gA1 + ks, sq + 4096 + w * 512); }                \
    BARM();                                                                    \
    PRIO1();                                                                   \
    _Pragma("unroll") for (int i = 0; i < 4; ++i)                              \
      _Pragma("unroll") for (int j = 0; j < 4; ++j)                            \
        acc[i][j] = mfma16h(a0[i], bh[j], acc[i][j]);                          \
    PRIO0();                                                                   \
    /* P2: read a1(cur); stage Bh; vmcnt -> tile t+1 resident; mma a0*bl */    \
    _Pragma("unroll") for (int i = 0; i < 4; ++i)                              \
      a1[i] = *(const f16x8*)&bb[(wm * 8 + 4 + i) * 512 + lane * 8];           \
    if (DO_STAGE) { GLOAD(Bh + gB0 + ks, sq + 8192 + w * 512);                 \
                    GLOAD(Bh + gB1 + ks, sq + 12288 + w * 512); }              \
    if ((WAITK) == 1) { WAITV4(); } else if ((WAITK) == 2) { WAITV0(); }       \
    BARM();                                                                    \
    PRIO1();                                                                   \
    _Pragma("unroll") for (int i = 0; i < 4; ++i)                              \
      _Pragma("unroll") for (int j = 0; j < 4; ++j)                            \
        acc[i][j] = mfma16h(a0[i], bl[j], acc[i][j]);                          \
    PRIO0();                                                                   \
    /* P3: preread a0'(nxt); stage Bl; mma a1*bh */                            \
    if (DO_PRE) { _Pragma("unroll") for (int i = 0; i < 4; ++i)                \
      a0[i] = *(const f16x8*)&nb[(wm * 8 + i) * 512 + lane * 8]; }             \
    if (DO_STAGE) { GLOAD(Bl + gB0 + ks, sq + 16384 + w * 512);                \
                    GLOAD(Bl + gB1 + ks, sq + 20480 + w * 512); }              \
    BARM();                                                                    \
    PRIO1();                                                                   \
    _Pragma("unroll") for (int i = 0; i < 4; ++i)                              \
      _Pragma("unroll") for (int j = 0; j < 4; ++j)                            \
        acc[4 + i][j] = mfma16h(a1[i], bh[j], acc[4 + i][j]);                  \
    PRIO0();                                                                   \
    /* P4: preread bh'(nxt); mma a1*bl */                                      \
    if (DO_PRE) { _Pragma("unroll") for (int j = 0; j < 4; ++j)                \
      bh[j] = *(const f16x8*)&nb[8192 + (wj * 4 + j) * 512 + lane * 8]; }      \
    BARM();                                                                    \
    PRIO1();                                                                   \
    _Pragma("unroll") for (int i = 0; i < 4; ++i)                              \
      _Pragma("unroll") for (int j = 0; j < 4; ++j)                            \
        acc[4 + i][j] = mfma16h(a1[i], bl[j], acc[4 + i][j]);                  \
    PRIO0();                                                                   \
  }

template <int EPI>
__global__ __launch_bounds__(512, 2) void gemm256_k(
    const _Float16* __restrict__ A,
    const _Float16* __restrict__ Bh, const _Float16* __restrict__ Bl,
    const float* __restrict__ bias, const float* __restrict__ valid,
    float* __restrict__ qf, float* __restrict__ kf, float* __restrict__ vv,
    float* __restrict__ outp, int jb, int jshift) {
  // per K-tile buffer: A 256x32 (8192 halfs) + Bh 8192 + Bl 8192 = 48 KiB; x3 = 144 KiB
  __shared__ _Float16 lds[73728];
  const int tid = threadIdx.x;
  const int lane = tid & 63, w = tid >> 6;
  const int lm = lane & 15, lq = lane >> 4;
  const int wm = w >> 2, wj = w & 3;

  // XCD swizzle (bijective: nwg is a multiple of 8 here: 512/256/256)
  const int nwg = gridDim.x;
  const int q8 = nwg >> 3;
  const int wid = (blockIdx.x & 7) * q8 + (blockIdx.x >> 3);
  const int j_blk = wid & ((1 << jshift) - 1);
  const int m_blk = wid >> jshift;
  const int m0 = m_blk * 256;
  const int jg0 = jb + j_blk * 256;

  // per-lane global source offsets (halfs); frag f = r*8 + w covers rows f*16+lm
  const size_t gA0 = (size_t)(m0 + w * 16 + lm) * GK + lq * 8;
  const size_t gA1 = gA0 + (size_t)128 * GK;
  const size_t gB0 = (size_t)(jg0 + w * 16 + lm) * GK + lq * 8;
  const size_t gB1 = gB0 + (size_t)128 * GK;

  // ---- prologue: stage tiles 0 (buf0) and 1 (buf1); wait tile0; preread ----
#pragma unroll
  for (int tt = 0; tt < 2; ++tt) {
    _Float16* sq = lds + tt * 24576;
    const size_t ks = (size_t)tt * 32;
    GLOAD(A + gA0 + ks, sq + w * 512);
    GLOAD(A + gA1 + ks, sq + 4096 + w * 512);
    GLOAD(Bh + gB0 + ks, sq + 8192 + w * 512);
    GLOAD(Bh + gB1 + ks, sq + 12288 + w * 512);
    GLOAD(Bl + gB0 + ks, sq + 16384 + w * 512);
    GLOAD(Bl + gB1 + ks, sq + 20480 + w * 512);
  }
  WAITV6();   // 12 outstanding -> oldest 6 (tile 0) complete
  BARM();

  f32x4 acc[8][4] = {};
  f16x8 a0[4], a1[4], bh[4], bl[4];
#pragma unroll
  for (int i = 0; i < 4; ++i)
    a0[i] = *(const f16x8*)&lds[(wm * 8 + i) * 512 + lane * 8];
#pragma unroll
  for (int j = 0; j < 4; ++j)
    bh[j] = *(const f16x8*)&lds[8192 + (wj * 4 + j) * 512 + lane * 8];

  // ---- main: tiles 0..29 with static buffer indices (10 x 3 unroll) ----
  for (int it = 0; it < 10; ++it) {
    const int t0 = 3 * it;
    TILE_BODY(0, true, true, 1, (size_t)(t0 + 2) * 32)
    TILE_BODY(1, true, true, 1, (size_t)(t0 + 3) * 32)
    TILE_BODY(2, true, true, 1, (size_t)(t0 + 4) * 32)
  }
  // ---- tail: tile 30 (buf 0; drain tile31 stages before preread), tile 31 ----
  TILE_BODY(0, false, true, 2, 0)
  TILE_BODY(1, false, false, 0, 0)

  // C/D layout: col = lane&15, row = (lane>>4)*4 + reg   [m89-verified]
  if (EPI == 0) {
    const int ty = jg0 >> 10;  // 0:q 1:k 2:v  (uniform per block: 256 | 1024)
    float* dst = (ty == 0) ? qf : ((ty == 1) ? kf : vv);
    float vld[8][4];
#pragma unroll
    for (int i = 0; i < 8; ++i)
#pragma unroll
      for (int r = 0; r < 4; ++r)
        vld[i][r] = (ty == 0) ? 1.0f : valid[m0 + wm * 128 + i * 16 + lq * 4 + r];
#pragma unroll
    for (int jt = 0; jt < 4; ++jt) {
      int jcol = jg0 + wj * 64 + jt * 16 + lm;
      float bj = bias[jcol];
      int c = jcol & 1023, hd = c >> 6, d = c & 63;
#pragma unroll
      for (int i = 0; i < 8; ++i)
#pragma unroll
        for (int r = 0; r < 4; ++r) {
          int m = m0 + wm * 128 + i * 16 + lq * 4 + r;
          int b = m >> 12, n = m & 4095;
          float val = acc[i][jt][r] + bj;
          if (ty <= 1) val = phi_f(val);
          if (ty >= 1) val *= vld[i][r];
          dst[(((size_t)(b * H_ + hd) * N_ + n) << 6) + d] = val;
        }
    }
  } else {
#pragma unroll
    for (int jt = 0; jt < 4; ++jt) {
      int jcol = jg0 + wj * 64 + jt * 16 + lm;
      float bj = bias[jcol];
#pragma unroll
      for (int i = 0; i < 8; ++i)
#pragma unroll
        for (int r = 0; r < 4; ++r) {
          int m = m0 + wm * 128 + i * 16 + lq * 4 + r;
          outp[(size_t)m * C_ + jcol] = acc[i][jt][r] + bj;
        }
    }
  }
}

// ---------------- kv partials: kv[bh][d][e] = sum_n kf[bh][n][d]*v[bh][n][e]; z[bh][d] ----------------
__global__ __launch_bounds__(256) void kv_partial_k(
    const float* __restrict__ kf, const float* __restrict__ vv,
    float* __restrict__ kvp, float* __restrict__ zp) {
  const int bh = blockIdx.x, ch = blockIdx.y;
  const float* kfr = kf + ((size_t)bh * N_ + ch * CHROWS) * 64;
  const float* vr  = vv + ((size_t)bh * N_ + ch * CHROWS) * 64;
  __shared__ float ks[8][64], vs[8][64];
  const int tid = threadIdx.x;
  const int d0 = tid >> 2, eg = tid & 3;
  float acc[16] = {};
  float zacc = 0.f;
  for (int nb = 0; nb < CHROWS; nb += 8) {
    {
      int which = tid >> 7;
      int fl = tid & 127;
      int rr = fl >> 4, cc = (fl & 15) * 4;
      const float* src = which ? vr : kfr;
      float4 t4 = *(const float4*)&src[(size_t)(nb + rr) * 64 + cc];
      float* d = which ? &vs[rr][cc] : &ks[rr][cc];
      *(float4*)d = t4;
    }
    __syncthreads();
#pragma unroll
    for (int r = 0; r < 8; ++r) {
      float kd = ks[r][d0];
      if (eg == 0) zacc += kd;
#pragma unroll
      for (int i = 0; i < 16; ++i) acc[i] += kd * vs[r][eg * 16 + i];
    }
    __syncthreads();
  }
  size_t base = ((size_t)bh * NCH + ch) * 4096 + (size_t)d0 * 64 + eg * 16;
#pragma unroll
  for (int i = 0; i < 16; i += 4)
    *(float4*)&kvp[base + i] = make_float4(acc[i], acc[i+1], acc[i+2], acc[i+3]);
  if (eg == 0) zp[((size_t)bh * NCH + ch) * 64 + d0] = zacc;
}

__global__ __launch_bounds__(256) void kv_reduce_k(
    const float* __restrict__ kvp, const float* __restrict__ zp,
    float* __restrict__ kv, float* __restrict__ z) {
  const int bh = blockIdx.x, tid = threadIdx.x;
  for (int i = tid; i < 4096; i += 256) {
    float s = 0.f;
#pragma unroll
    for (int c = 0; c < NCH; ++c) s += kvp[((size_t)bh * NCH + c) * 4096 + i];
    kv[(size_t)bh * 4096 + i] = s;
  }
  if (tid < 64) {
    float s = 0.f;
#pragma unroll
    for (int c = 0; c < NCH; ++c) s += zp[((size_t)bh * NCH + c) * 64 + tid];
    z[bh * 64 + tid] = s;
  }
}

// ---------------- apply: Y[b,n,h*64+e] = (qf . kv) / max(qf . z, eps), fp16 out ----------------
__global__ __launch_bounds__(256) void attn_apply_k(
    const float* __restrict__ qf, const float* __restrict__ kv,
    const float* __restrict__ z, _Float16* __restrict__ Y) {
  const int bh = blockIdx.x, nt = blockIdx.y;
  const int b = bh >> 4, hd = bh & 15;
  __shared__ float qs[128][65];
  __shared__ float kvs[64][68];
  __shared__ float zs[64];
  __shared__ float dens[128];
  const int tid = threadIdx.x;
  const float* qrow = qf + ((size_t)bh * N_ + nt * 128) * 64;
#pragma unroll
  for (int i = 0; i < 4; ++i) {
    int fl = tid + i * 256;
    int d = fl >> 4, cc = (fl & 15) * 4;
    float4 t4 = *(const float4*)&kv[(size_t)bh * 4096 + d * 64 + cc];
    kvs[d][cc] = t4.x; kvs[d][cc+1] = t4.y; kvs[d][cc+2] = t4.z; kvs[d][cc+3] = t4.w;
  }
  if (tid < 64) zs[tid] = z[bh * 64 + tid];
#pragma unroll
  for (int i = 0; i < 8; ++i) {
    int fl = tid + i * 256;
    int r = fl >> 4, cc = (fl & 15) * 4;
    float4 t4 = *(const float4*)&qrow[(size_t)r * 64 + cc];
    qs[r][cc] = t4.x; qs[r][cc+1] = t4.y; qs[r][cc+2] = t4.z; qs[r][cc+3] = t4.w;
  }
  __syncthreads();
  {
    int n = tid >> 1, half = tid & 1;
    float s = 0.f;
#pragma unroll
    for (int dd = 0; dd < 32; ++dd) {
      int d = half * 32 + dd;
      s += qs[n][d] * zs[d];
    }
    float other = __shfl_down(s, 1);
    if (half == 0) dens[n] = fmaxf(s + other, 1e-6f);
  }
  __syncthreads();
  const int ng = tid >> 3, eg = tid & 7;
  float acc[4][8] = {};
  for (int d = 0; d < 64; ++d) {
    float kvrow[8];
    *(float4*)&kvrow[0] = *(const float4*)&kvs[d][eg * 8];
    *(float4*)&kvrow[4] = *(const float4*)&kvs[d][eg * 8 + 4];
#pragma unroll
    for (int i = 0; i < 4; ++i) {
      float a = qs[ng * 4 + i][d];
#pragma unroll
      for (int j = 0; j < 8; ++j) acc[i][j] += a * kvrow[j];
    }
  }
#pragma unroll
  for (int i = 0; i < 4; ++i) {
    int nl = ng * 4 + i;
    int n = nt * 128 + nl;
    float inv = 1.0f / dens[nl];
    size_t off = ((size_t)b * N_ + n) * C_ + hd * 64 + eg * 8;
    f16x8 hv;
#pragma unroll
    for (int j = 0; j < 8; ++j) hv[j] = (_Float16)(acc[i][j] * inv);
    *(f16x8*)&Y[off] = hv;
  }
}

extern "C" void kernel_launch(void* const* d_in, const int* in_sizes, int n_in,
                              void* d_out, int out_size, void* d_ws, size_t ws_size,
                              hipStream_t stream) {
  const float* x      = (const float*)d_in[0];
  const float* W_qkv  = (const float*)d_in[1];
  const float* b_qkv  = (const float*)d_in[2];
  const float* W_out  = (const float*)d_in[3];
  const float* b_out  = (const float*)d_in[4];
  const void*  mask   = d_in[5];
  float* out = (float*)d_out;

  const size_t bhnd = (size_t)B_ * H_ * N_ * D_;   // 16,777,216
  float* ws = (float*)d_ws;
  float* buf1 = ws;                    // kf, then qf (fp32)
  float* buf2 = ws + bhnd;             // v (fp32), then Y (fp16)
  _Float16* Xh  = (_Float16*)(ws + 2 * bhnd);      // bhnd halfs
  _Float16* Wqh = Xh + bhnd;                       // 3072*1024
  _Float16* Wql = Wqh + (size_t)3072 * 1024;
  _Float16* Woh = Wql + (size_t)3072 * 1024;       // 1024*1024
  _Float16* Wol = Woh + (size_t)1024 * 1024;
  float* tail2 = (float*)(Wol + (size_t)1024 * 1024);
  float* kvp = tail2;                              // 64*8*4096
  float* zp  = kvp + (size_t)64 * NCH * 4096;
  float* kv  = zp + (size_t)64 * NCH * 64;
  float* z   = kv + (size_t)64 * 4096;
  float* valid = z + 64 * 64;
  int*   flag  = (int*)(valid + M_);

  _Float16* Y = (_Float16*)buf2;

  mask_detect_k<<<1, 256, 0, stream>>>((const unsigned int*)mask, flag);
  mask_convert_k<<<M_ / 256, 256, 0, stream>>>(mask, flag, valid);
  conv_f16_k<<<(int)(bhnd / 4 / 256), 256, 0, stream>>>(x, Xh, (int)(bhnd / 4));
  split_f16_k<<<3072 * 1024 / 4 / 256, 256, 0, stream>>>(W_qkv, Wqh, Wql, 3072 * 1024 / 4);
  split_f16_k<<<1024 * 1024 / 4 / 256, 256, 0, stream>>>(W_out, Woh, Wol, 1024 * 1024 / 4);
  // phase A: K and V projections (j in [1024,3072)) -> kf(buf1), v(buf2)
  // grid = 64 m-blocks x 8 j-blocks = 512 (1D, swizzled in-kernel)
  gemm256_k<0><<<512, 512, 0, stream>>>(
      Xh, Wqh, Wql, b_qkv, valid, buf1, buf1, buf2, nullptr, 1024, 3);
  kv_partial_k<<<dim3(B_ * H_, NCH), 256, 0, stream>>>(buf1, buf2, kvp, zp);
  kv_reduce_k<<<B_ * H_, 256, 0, stream>>>(kvp, zp, kv, z);
  // phase B: Q projection (j in [0,1024)) -> qf into buf1 (kf dead)
  gemm256_k<0><<<256, 512, 0, stream>>>(
      Xh, Wqh, Wql, b_qkv, valid, buf1, buf1, buf2, nullptr, 0, 2);
  // apply: reads qf(buf1), writes Y (fp16) into buf2 (v dead)
  attn_apply_k<<<dim3(B_ * H_, N_ / 128), 256, 0, stream>>>(buf1, kv, z, Y);
  // out-proj: A = Y (fp16 single), B = W_out split-2
  gemm256_k<1><<<256, 512, 0, stream>>>(
      Y, Woh, Wol, b_out, valid, nullptr, nullptr, nullptr, out, 0, 2);
}

// Round 6
// 483.773 us; speedup vs baseline: 1.0935x; 1.0207x over previous
//
#include <hip/hip_runtime.h>
#include <math.h>

#define B_ 4
#define N_ 4096
#define C_ 1024
#define H_ 16
#define D_ 64
#define M_ (B_*N_)      // 16384 rows
#define GK 1024         // GEMM K dim (both GEMMs)
#define NCH 8           // N-chunks for kv partial reduction
#define CHROWS (N_/NCH) // 512

typedef __attribute__((ext_vector_type(8))) _Float16 f16x8;
typedef __attribute__((ext_vector_type(4))) _Float16 f16x4;
typedef __attribute__((ext_vector_type(4))) float f32x4;

__device__ __forceinline__ float phi_f(float t) {
  return (t > 0.0f) ? (t + 1.0f) : __expf(t);
}

#define GLOAD(gp, lp) __builtin_amdgcn_global_load_lds( \
    (const __attribute__((address_space(1))) unsigned int*)(gp), \
    (__attribute__((address_space(3))) unsigned int*)(lp), 16, 0, 0)

#define BARM() asm volatile("s_barrier" ::: "memory")
#define WAITV6() asm volatile("s_waitcnt vmcnt(6)" ::: "memory")
#define WAITV4() asm volatile("s_waitcnt vmcnt(4)" ::: "memory")
#define WAITV0() asm volatile("s_waitcnt vmcnt(0)" ::: "memory")
#define PRIO1() __builtin_amdgcn_s_setprio(1)
#define PRIO0() __builtin_amdgcn_s_setprio(0)

__device__ __forceinline__ f32x4 mfma16h(f16x8 a, f16x8 b, f32x4 c) {
  return __builtin_amdgcn_mfma_f32_16x16x32_f16(a, b, c, 0, 0, 0);
}

// ---------------- fused prep: x->fp16, W splits, mask->valid ----------------
// block ranges: [0,16384) x conv | [16384,19456) Wqkv split | [19456,20480)
// Wout split | [20480,20544) mask.
// Mask dtype detection is CONTENT-based (never size-based: element counts are
// dtype-independent, so a size ratio can't distinguish bool from int32 and an
// int32 assumption on a bool buffer reads 48 KiB OOB).  Each mask block scans
// the first 4096 words (16 KiB -- in-bounds for every candidate dtype):
//   all words in {0,1}            -> int32 mask
//   all words in {0,0x3F800000}   -> float mask
//   otherwise                     -> byte mask (packed bools)
__global__ __launch_bounds__(256) void prep_k(
    const float* __restrict__ x, _Float16* __restrict__ Xh,
    const float* __restrict__ Wq, _Float16* __restrict__ Wqh, _Float16* __restrict__ Wql,
    const float* __restrict__ Wo, _Float16* __restrict__ Woh, _Float16* __restrict__ Wol,
    const void* __restrict__ mask, float* __restrict__ valid) {
  const int b = blockIdx.x, tid = threadIdx.x;
  if (b < 16384) {                       // x -> fp16 (single), float4 granule
    int i = b * 256 + tid;
    float4 v = ((const float4*)x)[i];
    f16x4 h;
    h[0] = (_Float16)v.x; h[1] = (_Float16)v.y;
    h[2] = (_Float16)v.z; h[3] = (_Float16)v.w;
    ((f16x4*)Xh)[i] = h;
  } else if (b < 19456) {                // W_qkv hi/lo split
    int i = (b - 16384) * 256 + tid;
    float4 v = ((const float4*)Wq)[i];
    float vs[4] = {v.x, v.y, v.z, v.w};
    f16x4 hv, lv;
#pragma unroll
    for (int q = 0; q < 4; ++q) {
      _Float16 hh = (_Float16)vs[q];
      lv[q] = (_Float16)(vs[q] - (float)hh);
      hv[q] = hh;
    }
    ((f16x4*)Wqh)[i] = hv;
    ((f16x4*)Wql)[i] = lv;
  } else if (b < 20480) {                // W_out hi/lo split
    int i = (b - 19456) * 256 + tid;
    float4 v = ((const float4*)Wo)[i];
    float vs[4] = {v.x, v.y, v.z, v.w};
    f16x4 hv, lv;
#pragma unroll
    for (int q = 0; q < 4; ++q) {
      _Float16 hh = (_Float16)vs[q];
      lv[q] = (_Float16)(vs[q] - (float)hh);
      hv[q] = hh;
    }
    ((f16x4*)Woh)[i] = hv;
    ((f16x4*)Wol)[i] = lv;
  } else {                               // mask -> valid (True = PAD -> 0)
    __shared__ unsigned int sni, snf;
    if (tid == 0) { sni = 0u; snf = 0u; }
    __syncthreads();
    const unsigned int* mw = (const unsigned int*)mask;
    unsigned int ni = 0, nf = 0;
    for (int t = tid; t < 4096; t += 256) {   // 16 KiB: in-bounds all dtypes
      unsigned int v = mw[t];
      ni |= (v > 1u) ? 1u : 0u;
      nf |= (v != 0u && v != 0x3F800000u) ? 1u : 0u;
    }
    if (ni) atomicOr(&sni, 1u);
    if (nf) atomicOr(&snf, 1u);
    __syncthreads();
    const int f = (!sni) ? 0 : ((!snf) ? 1 : 2);
    int i = (b - 20480) * 256 + tid;
    int m;
    if (f == 0)      m = ((const int*)mask)[i] != 0;          // int32: 64 KiB buf
    else if (f == 1) m = ((const float*)mask)[i] != 0.0f;     // float: 64 KiB buf
    else             m = ((const unsigned char*)mask)[i] != 0; // bool: 16 KiB buf
    valid[i] = m ? 0.0f : 1.0f;
  }
}

// ---------------- 2-term fp16 MFMA GEMM, 256x256 tile, balanced 4-phase ----------------
// out[m][j] = sum_k A[m][k] * (Bh[j][k] + Bl[j][k])
// 8 waves (2M x 4N), per-wave 128x64, K-tile 32, 3-deep LDS (144 KiB, static
// buffer indices via 10x3 unroll).  Per phase: 4 ds_reads (operands for the
// NEXT phase's MFMA -> compiler-counted lgkmcnt overlaps reads with MFMA),
// 2 global_load_lds, 1 barrier, 16 MFMA wrapped in setprio.  vmcnt(4) at P2
// proves tile t+1 is staged before P3/P4 preread it.
// XCD swizzle: j-major per XCD -> each XCD's B panel (256 cols x 1024 K x 2
// terms = 1 MB) stays L2-resident; A streams via L3.
// EPI 0: qkv epilogue (bias + phi/mask -> [B,H,N,D] fp32); EPI 1: bias + row-major fp32.

#define TILE_BODY(PC, DO_STAGE, DO_PRE, WAITK, KS)                             \
  {                                                                            \
    const _Float16* bb = lds + (PC) * 24576;                                   \
    const _Float16* nb = lds + (((PC) + 1) % 3) * 24576;                       \
    _Float16* sq = lds + (((PC) + 2) % 3) * 24576;                             \
    const size_t ks = (KS);                                                    \
    /* P1: read bl(cur); stage A; mma a0*bh */                                 \
    _Pragma("unroll") for (int j = 0; j < 4; ++j)                              \
      bl[j] = *(const f16x8*)&bb[16384 + (wj * 4 + j) * 512 + lane * 8];       \
    if (DO_STAGE) { GLOAD(A + gA0 + ks, sq + w * 512);                         \
                    GLOAD(A + gA1 + ks, sq + 4096 + w * 512); }                \
    BARM();                                                                    \
    PRIO1();                                                                   \
    _Pragma("unroll") for (int i = 0; i < 4; ++i)                              \
      _Pragma("unroll") for (int j = 0; j < 4; ++j)                            \
        acc[i][j] = mfma16h(a0[i], bh[j], acc[i][j]);                          \
    PRIO0();                                                                   \
    /* P2: read a1(cur); stage Bh; vmcnt -> tile t+1 resident; mma a0*bl */    \
    _Pragma("unroll") for (int i = 0; i < 4; ++i)                              \
      a1[i] = *(const f16x8*)&bb[(wm * 8 + 4 + i) * 512 + lane * 8];           \
    if (DO_STAGE) { GLOAD(Bh + gB0 + ks, sq + 8192 + w * 512);                 \
                    GLOAD(Bh + gB1 + ks, sq + 12288 + w * 512); }              \
    if ((WAITK) == 1) { WAITV4(); } else if ((WAITK) == 2) { WAITV0(); }       \
    BARM();                                                                    \
    PRIO1();                                                                   \
    _Pragma("unroll") for (int i = 0; i < 4; ++i)                              \
      _Pragma("unroll") for (int j = 0; j < 4; ++j)                            \
        acc[i][j] = mfma16h(a0[i], bl[j], acc[i][j]);                          \
    PRIO0();                                                                   \
    /* P3: preread a0'(nxt); stage Bl; mma a1*bh */                            \
    if (DO_PRE) { _Pragma("unroll") for (int i = 0; i < 4; ++i)                \
      a0[i] = *(const f16x8*)&nb[(wm * 8 + i) * 512 + lane * 8]; }             \
    if (DO_STAGE) { GLOAD(Bl + gB0 + ks, sq + 16384 + w * 512);                \
                    GLOAD(Bl + gB1 + ks, sq + 20480 + w * 512); }              \
    BARM();                                                                    \
    PRIO1();                                                                   \
    _Pragma("unroll") for (int i = 0; i < 4; ++i)                              \
      _Pragma("unroll") for (int j = 0; j < 4; ++j)                            \
        acc[4 + i][j] = mfma16h(a1[i], bh[j], acc[4 + i][j]);                  \
    PRIO0();                                                                   \
    /* P4: preread bh'(nxt); mma a1*bl */                                      \
    if (DO_PRE) { _Pragma("unroll") for (int j = 0; j < 4; ++j)                \
      bh[j] = *(const f16x8*)&nb[8192 + (wj * 4 + j) * 512 + lane * 8]; }      \
    BARM();                                                                    \
    PRIO1();                                                                   \
    _Pragma("unroll") for (int i = 0; i < 4; ++i)                              \
      _Pragma("unroll") for (int j = 0; j < 4; ++j)                            \
        acc[4 + i][j] = mfma16h(a1[i], bl[j], acc[4 + i][j]);                  \
    PRIO0();                                                                   \
  }

template <int EPI>
__global__ __launch_bounds__(512, 2) void gemm256_k(
    const _Float16* __restrict__ A,
    const _Float16* __restrict__ Bh, const _Float16* __restrict__ Bl,
    const float* __restrict__ bias, const float* __restrict__ valid,
    float* __restrict__ qf, float* __restrict__ kf, float* __restrict__ vv,
    float* __restrict__ outp, int jb) {
  // per K-tile buffer: A 256x32 (8192 halfs) + Bh 8192 + Bl 8192 = 48 KiB; x3 = 144 KiB
  __shared__ _Float16 lds[73728];
  const int tid = threadIdx.x;
  const int lane = tid & 63, w = tid >> 6;
  const int lm = lane & 15, lq = lane >> 4;
  const int wm = w >> 2, wj = w & 3;

  // XCD swizzle (bijective; nwg multiple of 8): consecutive bids round-robin
  // XCDs -> give each XCD a contiguous wid chunk; j-major so each XCD works
  // one j-panel (B stays in its private L2), m varies within.
  const int nwg = gridDim.x;
  const int q8 = nwg >> 3;
  const int wid = (blockIdx.x & 7) * q8 + (blockIdx.x >> 3);
  const int j_blk = wid >> 6;            // 64 m-blocks per j-panel
  const int m_blk = wid & 63;
  const int m0 = m_blk * 256;
  const int jg0 = jb + j_blk * 256;

  // per-lane global source offsets (halfs); frag f = r*8 + w covers rows f*16+lm
  const size_t gA0 = (size_t)(m0 + w * 16 + lm) * GK + lq * 8;
  const size_t gA1 = gA0 + (size_t)128 * GK;
  const size_t gB0 = (size_t)(jg0 + w * 16 + lm) * GK + lq * 8;
  const size_t gB1 = gB0 + (size_t)128 * GK;

  // ---- prologue: stage tiles 0 (buf0) and 1 (buf1); wait tile0; preread ----
#pragma unroll
  for (int tt = 0; tt < 2; ++tt) {
    _Float16* sq = lds + tt * 24576;
    const size_t ks = (size_t)tt * 32;
    GLOAD(A + gA0 + ks, sq + w * 512);
    GLOAD(A + gA1 + ks, sq + 4096 + w * 512);
    GLOAD(Bh + gB0 + ks, sq + 8192 + w * 512);
    GLOAD(Bh + gB1 + ks, sq + 12288 + w * 512);
    GLOAD(Bl + gB0 + ks, sq + 16384 + w * 512);
    GLOAD(Bl + gB1 + ks, sq + 20480 + w * 512);
  }
  WAITV6();   // 12 outstanding -> oldest 6 (tile 0) complete
  BARM();

  f32x4 acc[8][4] = {};
  f16x8 a0[4], a1[4], bh[4], bl[4];
#pragma unroll
  for (int i = 0; i < 4; ++i)
    a0[i] = *(const f16x8*)&lds[(wm * 8 + i) * 512 + lane * 8];
#pragma unroll
  for (int j = 0; j < 4; ++j)
    bh[j] = *(const f16x8*)&lds[8192 + (wj * 4 + j) * 512 + lane * 8];

  // ---- main: tiles 0..29 with static buffer indices (10 x 3 unroll) ----
  for (int it = 0; it < 10; ++it) {
    const int t0 = 3 * it;
    TILE_BODY(0, true, true, 1, (size_t)(t0 + 2) * 32)
    TILE_BODY(1, true, true, 1, (size_t)(t0 + 3) * 32)
    TILE_BODY(2, true, true, 1, (size_t)(t0 + 4) * 32)
  }
  // ---- tail: tile 30 (buf 0; drain tile31 stages before preread), tile 31 ----
  TILE_BODY(0, false, true, 2, 0)
  TILE_BODY(1, false, false, 0, 0)

  // C/D layout: col = lane&15, row = (lane>>4)*4 + reg   [m89-verified]
  if (EPI == 0) {
    const int ty = jg0 >> 10;  // 0:q 1:k 2:v  (uniform per block: 256 | 1024)
    float* dst = (ty == 0) ? qf : ((ty == 1) ? kf : vv);
    float vld[8][4];
#pragma unroll
    for (int i = 0; i < 8; ++i)
#pragma unroll
      for (int r = 0; r < 4; ++r)
        vld[i][r] = (ty == 0) ? 1.0f : valid[m0 + wm * 128 + i * 16 + lq * 4 + r];
#pragma unroll
    for (int jt = 0; jt < 4; ++jt) {
      int jcol = jg0 + wj * 64 + jt * 16 + lm;
      float bj = bias[jcol];
      int c = jcol & 1023, hd = c >> 6, d = c & 63;
#pragma unroll
      for (int i = 0; i < 8; ++i)
#pragma unroll
        for (int r = 0; r < 4; ++r) {
          int m = m0 + wm * 128 + i * 16 + lq * 4 + r;
          int b = m >> 12, n = m & 4095;
          float val = acc[i][jt][r] + bj;
          if (ty <= 1) val = phi_f(val);
          if (ty >= 1) val *= vld[i][r];
          dst[(((size_t)(b * H_ + hd) * N_ + n) << 6) + d] = val;
        }
    }
  } else {
#pragma unroll
    for (int jt = 0; jt < 4; ++jt) {
      int jcol = jg0 + wj * 64 + jt * 16 + lm;
      float bj = bias[jcol];
#pragma unroll
      for (int i = 0; i < 8; ++i)
#pragma unroll
        for (int r = 0; r < 4; ++r) {
          int m = m0 + wm * 128 + i * 16 + lq * 4 + r;
          outp[(size_t)m * C_ + jcol] = acc[i][jt][r] + bj;
        }
    }
  }
}

// ---------------- kv partials: kv[bh][d][e] = sum_n kf[bh][n][d]*v[bh][n][e]; z[bh][d] ----------------
// thread = (d4 = tid>>4 -> 4 d-rows, e4 = tid&15 -> 4 e-cols), acc[4][4].
// v staged 16 rows/round in LDS (1 b128/row/thread); kf read from GLOBAL as
// float4 (16 lanes share one 64B line -> L1 broadcast; VMEM pipe overlaps LDS
// pipe).  n-order ascending, NCH unchanged -> same summation order as before.
__global__ __launch_bounds__(256) void kv_partial_k(
    const float* __restrict__ kf, const float* __restrict__ vv,
    float* __restrict__ kvp, float* __restrict__ zp) {
  const int bh = blockIdx.x, ch = blockIdx.y;
  const float* kfr = kf + ((size_t)bh * N_ + ch * CHROWS) * 64;
  const float* vr  = vv + ((size_t)bh * N_ + ch * CHROWS) * 64;
  __shared__ float vs[16][64];
  const int tid = threadIdx.x;
  const int d4 = tid >> 4, e4 = tid & 15;
  const int srow = tid >> 4, scol = (tid & 15) * 4;
  float acc[4][4] = {};
  float zacc[4] = {};
  for (int nb = 0; nb < CHROWS; nb += 16) {
    float4 st = *(const float4*)&vr[(size_t)(nb + srow) * 64 + scol];
    __syncthreads();                       // prev round's reads done
    *(float4*)&vs[srow][scol] = st;
    float4 kq[16];
#pragma unroll
    for (int r = 0; r < 16; ++r)
      kq[r] = *(const float4*)&kfr[(size_t)(nb + r) * 64 + d4 * 4];
    __syncthreads();                       // vs visible
#pragma unroll
    for (int r = 0; r < 16; ++r) {
      float4 vq = *(const float4*)&vs[r][e4 * 4];
      float kk[4] = {kq[r].x, kq[r].y, kq[r].z, kq[r].w};
      float vk[4] = {vq.x, vq.y, vq.z, vq.w};
#pragma unroll
      for (int di = 0; di < 4; ++di) {
        if (e4 == 0) zacc[di] += kk[di];
#pragma unroll
        for (int ei = 0; ei < 4; ++ei) acc[di][ei] += kk[di] * vk[ei];
      }
    }
  }
  size_t base = ((size_t)bh * NCH + ch) * 4096 + (size_t)d4 * 4 * 64 + e4 * 4;
#pragma unroll
  for (int di = 0; di < 4; ++di)
    *(float4*)&kvp[base + (size_t)di * 64] =
        make_float4(acc[di][0], acc[di][1], acc[di][2], acc[di][3]);
  if (e4 == 0)
    *(float4*)&zp[((size_t)bh * NCH + ch) * 64 + d4 * 4] =
        make_float4(zacc[0], zacc[1], zacc[2], zacc[3]);
}

__global__ __launch_bounds__(256) void kv_reduce_k(
    const float* __restrict__ kvp, const float* __restrict__ zp,
    float* __restrict__ kv, float* __restrict__ z) {
  const int bh = blockIdx.x, tid = threadIdx.x;
  for (int i = tid; i < 4096; i += 256) {
    float s = 0.f;
#pragma unroll
    for (int c = 0; c < NCH; ++c) s += kvp[((size_t)bh * NCH + c) * 4096 + i];
    kv[(size_t)bh * 4096 + i] = s;
  }
  if (tid < 64) {
    float s = 0.f;
#pragma unroll
    for (int c = 0; c < NCH; ++c) s += zp[((size_t)bh * NCH + c) * 64 + tid];
    z[bh * 64 + tid] = s;
  }
}

// ---------------- apply: Y[b,n,h*64+e] = (qf . kv) / max(qf . z, eps), fp16 out ----------------
__global__ __launch_bounds__(256) void attn_apply_k(
    const float* __restrict__ qf, const float* __restrict__ kv,
    const float* __restrict__ z, _Float16* __restrict__ Y) {
  const int bh = blockIdx.x, nt = blockIdx.y;
  const int b = bh >> 4, hd = bh & 15;
  __shared__ float qs[128][65];
  __shared__ float kvs[64][68];
  __shared__ float zs[64];
  __shared__ float dens[128];
  const int tid = threadIdx.x;
  const float* qrow = qf + ((size_t)bh * N_ + nt * 128) * 64;
#pragma unroll
  for (int i = 0; i < 4; ++i) {
    int fl = tid + i * 256;
    int d = fl >> 4, cc = (fl & 15) * 4;
    float4 t4 = *(const float4*)&kv[(size_t)bh * 4096 + d * 64 + cc];
    kvs[d][cc] = t4.x; kvs[d][cc+1] = t4.y; kvs[d][cc+2] = t4.z; kvs[d][cc+3] = t4.w;
  }
  if (tid < 64) zs[tid] = z[bh * 64 + tid];
#pragma unroll
  for (int i = 0; i < 8; ++i) {
    int fl = tid + i * 256;
    int r = fl >> 4, cc = (fl & 15) * 4;
    float4 t4 = *(const float4*)&qrow[(size_t)r * 64 + cc];
    qs[r][cc] = t4.x; qs[r][cc+1] = t4.y; qs[r][cc+2] = t4.z; qs[r][cc+3] = t4.w;
  }
  __syncthreads();
  {
    int n = tid >> 1, half = tid & 1;
    float s = 0.f;
#pragma unroll
    for (int dd = 0; dd < 32; ++dd) {
      int d = half * 32 + dd;
      s += qs[n][d] * zs[d];
    }
    float other = __shfl_down(s, 1);
    if (half == 0) dens[n] = fmaxf(s + other, 1e-6f);
  }
  __syncthreads();
  const int ng = tid >> 3, eg = tid & 7;
  float acc[4][8] = {};
  for (int d = 0; d < 64; ++d) {
    float kvrow[8];
    *(float4*)&kvrow[0] = *(const float4*)&kvs[d][eg * 8];
    *(float4*)&kvrow[4] = *(const float4*)&kvs[d][eg * 8 + 4];
#pragma unroll
    for (int i = 0; i < 4; ++i) {
      float a = qs[ng * 4 + i][d];
#pragma unroll
      for (int j = 0; j < 8; ++j) acc[i][j] += a * kvrow[j];
    }
  }
#pragma unroll
  for (int i = 0; i < 4; ++i) {
    int nl = ng * 4 + i;
    int n = nt * 128 + nl;
    float inv = 1.0f / dens[nl];
    size_t off = ((size_t)b * N_ + n) * C_ + hd * 64 + eg * 8;
    f16x8 hv;
#pragma unroll
    for (int j = 0; j < 8; ++j) hv[j] = (_Float16)(acc[i][j] * inv);
    *(f16x8*)&Y[off] = hv;
  }
}

extern "C" void kernel_launch(void* const* d_in, const int* in_sizes, int n_in,
                              void* d_out, int out_size, void* d_ws, size_t ws_size,
                              hipStream_t stream) {
  const float* x      = (const float*)d_in[0];
  const float* W_qkv  = (const float*)d_in[1];
  const float* b_qkv  = (const float*)d_in[2];
  const float* W_out  = (const float*)d_in[3];
  const float* b_out  = (const float*)d_in[4];
  const void*  mask   = d_in[5];
  float* out = (float*)d_out;

  const size_t bhnd = (size_t)B_ * H_ * N_ * D_;   // 16,777,216
  float* ws = (float*)d_ws;
  float* buf1 = ws;                    // kf, then qf (fp32)
  float* buf2 = ws + bhnd;             // v (fp32), then Y (fp16)
  _Float16* Xh  = (_Float16*)(ws + 2 * bhnd);      // bhnd halfs
  _Float16* Wqh = Xh + bhnd;                       // 3072*1024
  _Float16* Wql = Wqh + (size_t)3072 * 1024;
  _Float16* Woh = Wql + (size_t)3072 * 1024;       // 1024*1024
  _Float16* Wol = Woh + (size_t)1024 * 1024;
  float* tail2 = (float*)(Wol + (size_t)1024 * 1024);
  float* kvp = tail2;                              // 64*8*4096
  float* zp  = kvp + (size_t)64 * NCH * 4096;
  float* kv  = zp + (size_t)64 * NCH * 64;
  float* z   = kv + (size_t)64 * 4096;
  float* valid = z + 64 * 64;

  _Float16* Y = (_Float16*)buf2;

  // fused prep: x conv + W splits + mask->valid (1 dispatch, 20544 blocks;
  // mask dtype detected by content inside the kernel, always in-bounds)
  prep_k<<<20544, 256, 0, stream>>>(x, Xh, W_qkv, Wqh, Wql, W_out, Woh, Wol,
                                    mask, valid);
  // phase A: K and V projections (j in [1024,3072)) -> kf(buf1), v(buf2)
  gemm256_k<0><<<512, 512, 0, stream>>>(
      Xh, Wqh, Wql, b_qkv, valid, buf1, buf1, buf2, nullptr, 1024);
  kv_partial_k<<<dim3(B_ * H_, NCH), 256, 0, stream>>>(buf1, buf2, kvp, zp);
  kv_reduce_k<<<B_ * H_, 256, 0, stream>>>(kvp, zp, kv, z);
  // phase B: Q projection (j in [0,1024)) -> qf into buf1 (kf dead)
  gemm256_k<0><<<256, 512, 0, stream>>>(
      Xh, Wqh, Wql, b_qkv, valid, buf1, buf1, buf2, nullptr, 0);
  // apply: reads qf(buf1), writes Y (fp16) into buf2 (v dead)
  attn_apply_k<<<dim3(B_ * H_, N_ / 128), 256, 0, stream>>>(buf1, kv, z, Y);
  // out-proj: A = Y (fp16 single), B = W_out split-2
  gemm256_k<1><<<256, 512, 0, stream>>>(
      Y, Woh, Wol, b_out, valid, nullptr, nullptr, nullptr, out, 0);
}

// Round 8
// 475.676 us; speedup vs baseline: 1.1122x; 1.0170x over previous
//
#include <hip/hip_runtime.h>
#include <math.h>

#define B_ 4
#define N_ 4096
#define C_ 1024
#define H_ 16
#define D_ 64
#define M_ (B_*N_)      // 16384 rows
#define GK 1024         // GEMM K dim (both GEMMs)
#define NCH 8           // N-chunks for kv partial reduction
#define CHROWS (N_/NCH) // 512

typedef __attribute__((ext_vector_type(8))) _Float16 f16x8;
typedef __attribute__((ext_vector_type(4))) _Float16 f16x4;
typedef __attribute__((ext_vector_type(4))) float f32x4;

__device__ __forceinline__ float phi_f(float t) {
  return (t > 0.0f) ? (t + 1.0f) : __expf(t);
}

#define GLOAD(gp, lp) __builtin_amdgcn_global_load_lds( \
    (const __attribute__((address_space(1))) unsigned int*)(gp), \
    (__attribute__((address_space(3))) unsigned int*)(lp), 16, 0, 0)

#define BARM() asm volatile("s_barrier" ::: "memory")
#define WAITV6() asm volatile("s_waitcnt vmcnt(6)" ::: "memory")
#define WAITV4() asm volatile("s_waitcnt vmcnt(4)" ::: "memory")
#define WAITV0() asm volatile("s_waitcnt vmcnt(0)" ::: "memory")
#define WAITL0() asm volatile("s_waitcnt lgkmcnt(0)" ::: "memory")
#define SCHEDB() __builtin_amdgcn_sched_barrier(0)
#define PRIO1() __builtin_amdgcn_s_setprio(1)
#define PRIO0() __builtin_amdgcn_s_setprio(0)

__device__ __forceinline__ f32x4 mfma16h(f16x8 a, f16x8 b, f32x4 c) {
  return __builtin_amdgcn_mfma_f32_16x16x32_f16(a, b, c, 0, 0, 0);
}

// ---------------- fused prep: x->fp16, W splits, mask->valid ----------------
// block ranges: [0,16384) x conv | [16384,19456) Wqkv split | [19456,20480)
// Wout split | [20480,20544) mask.  Mask dtype detection is CONTENT-based
// (size ratios can't distinguish bool from int32 when sizes are in elements;
// the wrong guess reads 48 KiB OOB).  Scan of first 4096 words is in-bounds
// for every candidate dtype.
__global__ __launch_bounds__(256) void prep_k(
    const float* __restrict__ x, _Float16* __restrict__ Xh,
    const float* __restrict__ Wq, _Float16* __restrict__ Wqh, _Float16* __restrict__ Wql,
    const float* __restrict__ Wo, _Float16* __restrict__ Woh, _Float16* __restrict__ Wol,
    const void* __restrict__ mask, float* __restrict__ valid) {
  const int b = blockIdx.x, tid = threadIdx.x;
  if (b < 16384) {                       // x -> fp16 (single), float4 granule
    int i = b * 256 + tid;
    float4 v = ((const float4*)x)[i];
    f16x4 h;
    h[0] = (_Float16)v.x; h[1] = (_Float16)v.y;
    h[2] = (_Float16)v.z; h[3] = (_Float16)v.w;
    ((f16x4*)Xh)[i] = h;
  } else if (b < 19456) {                // W_qkv hi/lo split
    int i = (b - 16384) * 256 + tid;
    float4 v = ((const float4*)Wq)[i];
    float vs[4] = {v.x, v.y, v.z, v.w};
    f16x4 hv, lv;
#pragma unroll
    for (int q = 0; q < 4; ++q) {
      _Float16 hh = (_Float16)vs[q];
      lv[q] = (_Float16)(vs[q] - (float)hh);
      hv[q] = hh;
    }
    ((f16x4*)Wqh)[i] = hv;
    ((f16x4*)Wql)[i] = lv;
  } else if (b < 20480) {                // W_out hi/lo split
    int i = (b - 19456) * 256 + tid;
    float4 v = ((const float4*)Wo)[i];
    float vs[4] = {v.x, v.y, v.z, v.w};
    f16x4 hv, lv;
#pragma unroll
    for (int q = 0; q < 4; ++q) {
      _Float16 hh = (_Float16)vs[q];
      lv[q] = (_Float16)(vs[q] - (float)hh);
      hv[q] = hh;
    }
    ((f16x4*)Woh)[i] = hv;
    ((f16x4*)Wol)[i] = lv;
  } else {                               // mask -> valid (True = PAD -> 0)
    __shared__ unsigned int sni, snf;
    if (tid == 0) { sni = 0u; snf = 0u; }
    __syncthreads();
    const unsigned int* mw = (const unsigned int*)mask;
    unsigned int ni = 0, nf = 0;
    for (int t = tid; t < 4096; t += 256) {   // 16 KiB: in-bounds all dtypes
      unsigned int v = mw[t];
      ni |= (v > 1u) ? 1u : 0u;
      nf |= (v != 0u && v != 0x3F800000u) ? 1u : 0u;
    }
    if (ni) atomicOr(&sni, 1u);
    if (nf) atomicOr(&snf, 1u);
    __syncthreads();
    const int f = (!sni) ? 0 : ((!snf) ? 1 : 2);
    int i = (b - 20480) * 256 + tid;
    int m;
    if (f == 0)      m = ((const int*)mask)[i] != 0;
    else if (f == 1) m = ((const float*)mask)[i] != 0.0f;
    else             m = ((const unsigned char*)mask)[i] != 0;
    valid[i] = m ? 0.0f : 1.0f;
  }
}

// ---------------- 2-term fp16 MFMA GEMM, 256x256 tile, balanced 4-phase ----------------
// out[m][j] = sum_k A[m][k] * (Bh[j][k] + Bl[j][k])
// 8 waves (2M x 4N), per-wave 128x64, K-tile 32, 3-deep LDS (144 KiB).
// XCD swizzle: r3's proven m-major form (8m x nj patch per XCD; the r4/r6
// j-major variant raised FETCH_SIZE 84->142 MB and cost 7 us).
// EPI 0: qkv epilogue (bias + phi/mask -> [B,H,N,D] fp32)
// EPI 1: bias + row-major fp32 (out-proj)
// EPI 2: fused Q-proj + linear-attention apply:
//   each wave holds one head's full d=64 for 128 rows in acc.  den via
//   4x shfl_xor; num via MFMA after an in-LDS C->A-frag transpose
//   (XOR-swizzled, G4) against kvT staged as fp16 hi/lo by kv_reduce.
//   3-term product keeps fp32-level accuracy.  Writes Y fp16 directly.
//   (r7 bug fixed here: z index must include the batch offset --
//   z is [b*H+h][64]; using head-only silently used batch 0's z.)

#define TILE_BODY(PC, DO_STAGE, DO_PRE, WAITK, KS)                             \
  {                                                                            \
    const _Float16* bb = lds + (PC) * 24576;                                   \
    const _Float16* nb = lds + (((PC) + 1) % 3) * 24576;                       \
    _Float16* sq = lds + (((PC) + 2) % 3) * 24576;                             \
    const size_t ks = (KS);                                                    \
    /* P1: read bl(cur); stage A; mma a0*bh */                                 \
    _Pragma("unroll") for (int j = 0; j < 4; ++j)                              \
      bl[j] = *(const f16x8*)&bb[16384 + (wj * 4 + j) * 512 + lane * 8];       \
    if (DO_STAGE) { GLOAD(A + gA0 + ks, sq + w * 512);                         \
                    GLOAD(A + gA1 + ks, sq + 4096 + w * 512); }                \
    BARM();                                                                    \
    PRIO1();                                                                   \
    _Pragma("unroll") for (int i = 0; i < 4; ++i)                              \
      _Pragma("unroll") for (int j = 0; j < 4; ++j)                            \
        acc[i][j] = mfma16h(a0[i], bh[j], acc[i][j]);                          \
    PRIO0();                                                                   \
    /* P2: read a1(cur); stage Bh; vmcnt -> tile t+1 resident; mma a0*bl */    \
    _Pragma("unroll") for (int i = 0; i < 4; ++i)                              \
      a1[i] = *(const f16x8*)&bb[(wm * 8 + 4 + i) * 512 + lane * 8];           \
    if (DO_STAGE) { GLOAD(Bh + gB0 + ks, sq + 8192 + w * 512);                 \
                    GLOAD(Bh + gB1 + ks, sq + 12288 + w * 512); }              \
    if ((WAITK) == 1) { WAITV4(); } else if ((WAITK) == 2) { WAITV0(); }       \
    BARM();                                                                    \
    PRIO1();                                                                   \
    _Pragma("unroll") for (int i = 0; i < 4; ++i)                              \
      _Pragma("unroll") for (int j = 0; j < 4; ++j)                            \
        acc[i][j] = mfma16h(a0[i], bl[j], acc[i][j]);                          \
    PRIO0();                                                                   \
    /* P3: preread a0'(nxt); stage Bl; mma a1*bh */                            \
    if (DO_PRE) { _Pragma("unroll") for (int i = 0; i < 4; ++i)                \
      a0[i] = *(const f16x8*)&nb[(wm * 8 + i) * 512 + lane * 8]; }             \
    if (DO_STAGE) { GLOAD(Bl + gB0 + ks, sq + 16384 + w * 512);                \
                    GLOAD(Bl + gB1 + ks, sq + 20480 + w * 512); }              \
    BARM();                                                                    \
    PRIO1();                                                                   \
    _Pragma("unroll") for (int i = 0; i < 4; ++i)                              \
      _Pragma("unroll") for (int j = 0; j < 4; ++j)                            \
        acc[4 + i][j] = mfma16h(a1[i], bh[j], acc[4 + i][j]);                  \
    PRIO0();                                                                   \
    /* P4: preread bh'(nxt); mma a1*bl */                                      \
    if (DO_PRE) { _Pragma("unroll") for (int j = 0; j < 4; ++j)                \
      bh[j] = *(const f16x8*)&nb[8192 + (wj * 4 + j) * 512 + lane * 8]; }      \
    BARM();                                                                    \
    PRIO1();                                                                   \
    _Pragma("unroll") for (int i = 0; i < 4; ++i)                              \
      _Pragma("unroll") for (int j = 0; j < 4; ++j)                            \
        acc[4 + i][j] = mfma16h(a1[i], bl[j], acc[4 + i][j]);                  \
    PRIO0();                                                                   \
  }

template <int EPI>
__global__ __launch_bounds__(512, 2) void gemm256_k(
    const _Float16* __restrict__ A,
    const _Float16* __restrict__ Bh, const _Float16* __restrict__ Bl,
    const float* __restrict__ bias, const float* __restrict__ valid,
    float* __restrict__ qf, float* __restrict__ kf, float* __restrict__ vv,
    float* __restrict__ outp, int jb, int jshift,
    const _Float16* __restrict__ kvt_h, const _Float16* __restrict__ kvt_l,
    const float* __restrict__ zv, _Float16* __restrict__ Yo) {
  // per K-tile buffer: A 256x32 (8192 halfs) + Bh 8192 + Bl 8192 = 48 KiB; x3 = 144 KiB
  __shared__ _Float16 lds[73728];
  const int tid = threadIdx.x;
  const int lane = tid & 63, w = tid >> 6;
  const int lm = lane & 15, lq = lane >> 4;
  const int wm = w >> 2, wj = w & 3;

  // XCD swizzle (bijective; nwg multiple of 8), r3 form: m-major within each
  // XCD's contiguous wid chunk -> compact 2D patch per XCD.
  const int nwg = gridDim.x;
  const int q8 = nwg >> 3;
  const int wid = (blockIdx.x & 7) * q8 + (blockIdx.x >> 3);
  const int j_blk = wid & ((1 << jshift) - 1);
  const int m_blk = wid >> jshift;
  const int m0 = m_blk * 256;
  const int jg0 = jb + j_blk * 256;

  // per-lane global source offsets (halfs); frag f = r*8 + w covers rows f*16+lm
  const size_t gA0 = (size_t)(m0 + w * 16 + lm) * GK + lq * 8;
  const size_t gA1 = gA0 + (size_t)128 * GK;
  const size_t gB0 = (size_t)(jg0 + w * 16 + lm) * GK + lq * 8;
  const size_t gB1 = gB0 + (size_t)128 * GK;

  // ---- prologue: stage tiles 0 (buf0) and 1 (buf1); wait tile0; preread ----
#pragma unroll
  for (int tt = 0; tt < 2; ++tt) {
    _Float16* sq = lds + tt * 24576;
    const size_t ks = (size_t)tt * 32;
    GLOAD(A + gA0 + ks, sq + w * 512);
    GLOAD(A + gA1 + ks, sq + 4096 + w * 512);
    GLOAD(Bh + gB0 + ks, sq + 8192 + w * 512);
    GLOAD(Bh + gB1 + ks, sq + 12288 + w * 512);
    GLOAD(Bl + gB0 + ks, sq + 16384 + w * 512);
    GLOAD(Bl + gB1 + ks, sq + 20480 + w * 512);
  }
  WAITV6();   // 12 outstanding -> oldest 6 (tile 0) complete
  BARM();

  f32x4 acc[8][4] = {};
  f16x8 a0[4], a1[4], bh[4], bl[4];
#pragma unroll
  for (int i = 0; i < 4; ++i)
    a0[i] = *(const f16x8*)&lds[(wm * 8 + i) * 512 + lane * 8];
#pragma unroll
  for (int j = 0; j < 4; ++j)
    bh[j] = *(const f16x8*)&lds[8192 + (wj * 4 + j) * 512 + lane * 8];

  // ---- main: tiles 0..29 with static buffer indices (10 x 3 unroll) ----
  for (int it = 0; it < 10; ++it) {
    const int t0 = 3 * it;
    TILE_BODY(0, true, true, 1, (size_t)(t0 + 2) * 32)
    TILE_BODY(1, true, true, 1, (size_t)(t0 + 3) * 32)
    TILE_BODY(2, true, true, 1, (size_t)(t0 + 4) * 32)
  }
  // ---- tail: tile 30 (buf 0; drain tile31 stages before preread), tile 31 ----
  TILE_BODY(0, false, true, 2, 0)
  TILE_BODY(1, false, false, 0, 0)

  // C/D layout: col = lane&15, row = (lane>>4)*4 + reg   [m89-verified]
  if (EPI == 0) {
    const int ty = jg0 >> 10;  // 1:k 2:v  (uniform per block)
    float* dst = (ty == 0) ? qf : ((ty == 1) ? kf : vv);
    float vld[8][4];
#pragma unroll
    for (int i = 0; i < 8; ++i)
#pragma unroll
      for (int r = 0; r < 4; ++r)
        vld[i][r] = (ty == 0) ? 1.0f : valid[m0 + wm * 128 + i * 16 + lq * 4 + r];
#pragma unroll
    for (int jt = 0; jt < 4; ++jt) {
      int jcol = jg0 + wj * 64 + jt * 16 + lm;
      float bj = bias[jcol];
      int c = jcol & 1023, hd = c >> 6, d = c & 63;
#pragma unroll
      for (int i = 0; i < 8; ++i)
#pragma unroll
        for (int r = 0; r < 4; ++r) {
          int m = m0 + wm * 128 + i * 16 + lq * 4 + r;
          int b = m >> 12, n = m & 4095;
          float val = acc[i][jt][r] + bj;
          if (ty <= 1) val = phi_f(val);
          if (ty >= 1) val *= vld[i][r];
          dst[(((size_t)(b * H_ + hd) * N_ + n) << 6) + d] = val;
        }
    }
  } else if (EPI == 1) {
#pragma unroll
    for (int jt = 0; jt < 4; ++jt) {
      int jcol = jg0 + wj * 64 + jt * 16 + lm;
      float bj = bias[jcol];
#pragma unroll
      for (int i = 0; i < 8; ++i)
#pragma unroll
        for (int r = 0; r < 4; ++r) {
          int m = m0 + wm * 128 + i * 16 + lq * 4 + r;
          outp[(size_t)m * C_ + jcol] = acc[i][jt][r] + bj;
        }
    }
  } else {
    // ---- EPI 2: fused Q-projection + apply ----
    const int head = (jg0 >> 6) + wj;          // j_blk*4 + wj
    const int bidx = m0 >> 12;                 // one batch per 256-row block
    const int bh_idx = bidx * H_ + head;
    const size_t kvbase = (size_t)bh_idx * 4096;
    // 1. val = phi(q + bias) in place; den = 1/max(qf.z, eps) per row
    float breg[4], zreg[4];
#pragma unroll
    for (int jt = 0; jt < 4; ++jt) {
      breg[jt] = bias[jg0 + wj * 64 + jt * 16 + lm];
      zreg[jt] = zv[bh_idx * 64 + jt * 16 + lm];   // r7 fix: batch offset!
    }
    float den[8][4];
#pragma unroll
    for (int i = 0; i < 8; ++i)
#pragma unroll
      for (int r = 0; r < 4; ++r) {
        float p = 0.f;
#pragma unroll
        for (int jt = 0; jt < 4; ++jt) {
          float v = phi_f(acc[i][jt][r] + breg[jt]);
          acc[i][jt][r] = v;
          p += v * zreg[jt];
        }
        p += __shfl_xor(p, 1); p += __shfl_xor(p, 2);
        p += __shfl_xor(p, 4); p += __shfl_xor(p, 8);
        den[i][r] = 1.0f / fmaxf(p, 1e-6f);
      }
    // 2. all waves done with K-loop LDS -> safe to reuse as transpose scratch
    BARM();
    char* sb = (char*)(lds) + w * 16384;       // 16 KiB private slice per wave
    // 3. two row-halves: transpose C-frags -> A-frags (hi/lo fp16), PV MFMA
#pragma unroll
    for (int h = 0; h < 2; ++h) {
#pragma unroll
      for (int i2 = 0; i2 < 4; ++i2) {
#pragma unroll
        for (int jt = 0; jt < 4; ++jt)
#pragma unroll
          for (int r = 0; r < 4; ++r) {
            int row = i2 * 16 + lq * 4 + r;    // 0..63 within half
            int d = jt * 16 + lm;
            float v = acc[h * 4 + i2][jt][r];
            _Float16 vh = (_Float16)v;
            _Float16 vl = (_Float16)(v - (float)vh);
            int bo = (row * 128 + d * 2) ^ ((row & 7) << 4);  // G4 swizzle
            *(_Float16*)(sb + bo) = vh;
            *(_Float16*)(sb + 8192 + bo) = vl;
          }
      }
      WAITL0(); SCHEDB();                      // writes land before reads
      f32x4 acc2[4][4] = {};
#pragma unroll
      for (int ks = 0; ks < 2; ++ks) {
        f16x8 ah[4], al[4], bhf[4], blf[4];
#pragma unroll
        for (int f = 0; f < 4; ++f) {
          int row = f * 16 + lm;
          int bo = (row * 128 + ks * 64 + lq * 16) ^ ((row & 7) << 4);
          ah[f] = *(const f16x8*)(sb + bo);
          al[f] = *(const f16x8*)(sb + 8192 + bo);
        }
#pragma unroll
        for (int et = 0; et < 4; ++et) {
          size_t go = kvbase + (size_t)(et * 16 + lm) * 64 + ks * 32 + lq * 8;
          bhf[et] = *(const f16x8*)&kvt_h[go];
          blf[et] = *(const f16x8*)&kvt_l[go];
        }
#pragma unroll
        for (int f = 0; f < 4; ++f)
#pragma unroll
          for (int et = 0; et < 4; ++et) {
            acc2[f][et] = mfma16h(ah[f], bhf[et], acc2[f][et]);
            acc2[f][et] = mfma16h(ah[f], blf[et], acc2[f][et]);
            acc2[f][et] = mfma16h(al[f], bhf[et], acc2[f][et]);
          }
      }
      // 4. y = num * (1/den), fp16, direct to Y
#pragma unroll
      for (int f = 0; f < 4; ++f)
#pragma unroll
        for (int et = 0; et < 4; ++et)
#pragma unroll
          for (int r = 0; r < 4; ++r) {
            int m = m0 + wm * 128 + h * 64 + f * 16 + lq * 4 + r;
            float yv = acc2[f][et][r] * den[h * 4 + f][r];
            Yo[(size_t)m * C_ + head * 64 + et * 16 + lm] = (_Float16)yv;
          }
      WAITL0(); SCHEDB();                      // half1 reads done before half2 writes
    }
  }
}

// ---------------- kv partials: kv[bh][d][e] = sum_n kf[bh][n][d]*v[bh][n][e]; z[bh][d] ----------------
__global__ __launch_bounds__(256) void kv_partial_k(
    const float* __restrict__ kf, const float* __restrict__ vv,
    float* __restrict__ kvp, float* __restrict__ zp) {
  const int bh = blockIdx.x, ch = blockIdx.y;
  const float* kfr = kf + ((size_t)bh * N_ + ch * CHROWS) * 64;
  const float* vr  = vv + ((size_t)bh * N_ + ch * CHROWS) * 64;
  __shared__ float vs[16][64];
  const int tid = threadIdx.x;
  const int d4 = tid >> 4, e4 = tid & 15;
  const int srow = tid >> 4, scol = (tid & 15) * 4;
  float acc[4][4] = {};
  float zacc[4] = {};
  for (int nb = 0; nb < CHROWS; nb += 16) {
    float4 st = *(const float4*)&vr[(size_t)(nb + srow) * 64 + scol];
    __syncthreads();                       // prev round's reads done
    *(float4*)&vs[srow][scol] = st;
    float4 kq[16];
#pragma unroll
    for (int r = 0; r < 16; ++r)
      kq[r] = *(const float4*)&kfr[(size_t)(nb + r) * 64 + d4 * 4];
    __syncthreads();                       // vs visible
#pragma unroll
    for (int r = 0; r < 16; ++r) {
      float4 vq = *(const float4*)&vs[r][e4 * 4];
      float kk[4] = {kq[r].x, kq[r].y, kq[r].z, kq[r].w};
      float vk[4] = {vq.x, vq.y, vq.z, vq.w};
#pragma unroll
      for (int di = 0; di < 4; ++di) {
        if (e4 == 0) zacc[di] += kk[di];
#pragma unroll
        for (int ei = 0; ei < 4; ++ei) acc[di][ei] += kk[di] * vk[ei];
      }
    }
  }
  size_t base = ((size_t)bh * NCH + ch) * 4096 + (size_t)d4 * 4 * 64 + e4 * 4;
#pragma unroll
  for (int di = 0; di < 4; ++di)
    *(float4*)&kvp[base + (size_t)di * 64] =
        make_float4(acc[di][0], acc[di][1], acc[di][2], acc[di][3]);
  if (e4 == 0)
    *(float4*)&zp[((size_t)bh * NCH + ch) * 64 + d4 * 4] =
        make_float4(zacc[0], zacc[1], zacc[2], zacc[3]);
}

// reduce partials -> kvT (fp16 hi/lo, [bh][e][d] -- B-fragment-ready) + z fp32
__global__ __launch_bounds__(256) void kv_reduce_k(
    const float* __restrict__ kvp, const float* __restrict__ zp,
    _Float16* __restrict__ kvt_h, _Float16* __restrict__ kvt_l,
    float* __restrict__ z) {
  const int bh = blockIdx.x, tid = threadIdx.x;
  for (int i = tid; i < 4096; i += 256) {
    float s = 0.f;
#pragma unroll
    for (int c = 0; c < NCH; ++c) s += kvp[((size_t)bh * NCH + c) * 4096 + i];
    int d = i >> 6, e = i & 63;
    _Float16 sh = (_Float16)s;
    kvt_h[(size_t)bh * 4096 + e * 64 + d] = sh;
    kvt_l[(size_t)bh * 4096 + e * 64 + d] = (_Float16)(s - (float)sh);
  }
  if (tid < 64) {
    float s = 0.f;
#pragma unroll
    for (int c = 0; c < NCH; ++c) s += zp[((size_t)bh * NCH + c) * 64 + tid];
    z[bh * 64 + tid] = s;
  }
}

extern "C" void kernel_launch(void* const* d_in, const int* in_sizes, int n_in,
                              void* d_out, int out_size, void* d_ws, size_t ws_size,
                              hipStream_t stream) {
  const float* x      = (const float*)d_in[0];
  const float* W_qkv  = (const float*)d_in[1];
  const float* b_qkv  = (const float*)d_in[2];
  const float* W_out  = (const float*)d_in[3];
  const float* b_out  = (const float*)d_in[4];
  const void*  mask   = d_in[5];
  float* out = (float*)d_out;

  const size_t bhnd = (size_t)B_ * H_ * N_ * D_;   // 16,777,216
  float* ws = (float*)d_ws;
  float* buf1 = ws;                    // kf (fp32)
  float* buf2 = ws + bhnd;             // v (fp32), then Y (fp16)
  _Float16* Xh  = (_Float16*)(ws + 2 * bhnd);      // bhnd halfs
  _Float16* Wqh = Xh + bhnd;                       // 3072*1024
  _Float16* Wql = Wqh + (size_t)3072 * 1024;
  _Float16* Woh = Wql + (size_t)3072 * 1024;       // 1024*1024
  _Float16* Wol = Woh + (size_t)1024 * 1024;
  float* tail2 = (float*)(Wol + (size_t)1024 * 1024);
  float* kvp = tail2;                              // 64*8*4096
  float* zp  = kvp + (size_t)64 * NCH * 4096;
  float* z   = zp + (size_t)64 * NCH * 64;
  float* valid = z + 64 * 64;
  _Float16* kvt_h = (_Float16*)(valid + M_);       // 64*4096 halfs
  _Float16* kvt_l = kvt_h + (size_t)64 * 4096;

  _Float16* Y = (_Float16*)buf2;

  // fused prep: x conv + W splits + mask->valid (1 dispatch, 20544 blocks)
  prep_k<<<20544, 256, 0, stream>>>(x, Xh, W_qkv, Wqh, Wql, W_out, Woh, Wol,
                                    mask, valid);
  // phase A: K and V projections (j in [1024,3072)) -> kf(buf1), v(buf2)
  gemm256_k<0><<<512, 512, 0, stream>>>(
      Xh, Wqh, Wql, b_qkv, valid, buf1, buf1, buf2, nullptr, 1024, 3,
      nullptr, nullptr, nullptr, nullptr);
  kv_partial_k<<<dim3(B_ * H_, NCH), 256, 0, stream>>>(buf1, buf2, kvp, zp);
  kv_reduce_k<<<B_ * H_, 256, 0, stream>>>(kvp, zp, kvt_h, kvt_l, z);
  // phase B: fused Q projection + apply -> Y (fp16) into buf2 (v dead)
  gemm256_k<2><<<256, 512, 0, stream>>>(
      Xh, Wqh, Wql, b_qkv, valid, nullptr, nullptr, nullptr, nullptr, 0, 2,
      kvt_h, kvt_l, z, Y);
  // out-proj: A = Y (fp16 single), B = W_out split-2
  gemm256_k<1><<<256, 512, 0, stream>>>(
      Y, Woh, Wol, b_out, valid, nullptr, nullptr, nullptr, out, 0, 2,
      nullptr, nullptr, nullptr, nullptr);
}

// Round 9
// 402.121 us; speedup vs baseline: 1.3156x; 1.1829x over previous
//
#include <hip/hip_runtime.h>
#include <math.h>

#define B_ 4
#define N_ 4096
#define C_ 1024
#define H_ 16
#define D_ 64
#define M_ (B_*N_)      // 16384 rows
#define GK 1024         // GEMM K dim (both GEMMs)
#define NCH 8           // N-chunks for kv partial reduction
#define CHROWS (N_/NCH) // 512

typedef __attribute__((ext_vector_type(8))) _Float16 f16x8;
typedef __attribute__((ext_vector_type(4))) _Float16 f16x4;
typedef __attribute__((ext_vector_type(4))) float f32x4;

__device__ __forceinline__ float phi_f(float t) {
  return (t > 0.0f) ? (t + 1.0f) : __expf(t);
}

#define GLOAD(gp, lp) __builtin_amdgcn_global_load_lds( \
    (const __attribute__((address_space(1))) unsigned int*)(gp), \
    (__attribute__((address_space(3))) unsigned int*)(lp), 16, 0, 0)

#define BARM() asm volatile("s_barrier" ::: "memory")
#define WAITV4() asm volatile("s_waitcnt vmcnt(4)" ::: "memory")
#define WAITV2() asm volatile("s_waitcnt vmcnt(2)" ::: "memory")
#define WAITV0() asm volatile("s_waitcnt vmcnt(0)" ::: "memory")
#define WAITL0() asm volatile("s_waitcnt lgkmcnt(0)" ::: "memory")
#define SCHEDB() __builtin_amdgcn_sched_barrier(0)
#define PRIO1() __builtin_amdgcn_s_setprio(1)
#define PRIO0() __builtin_amdgcn_s_setprio(0)

__device__ __forceinline__ f32x4 mfma16h(f16x8 a, f16x8 b, f32x4 c) {
  return __builtin_amdgcn_mfma_f32_16x16x32_f16(a, b, c, 0, 0, 0);
}

// ---------------- fused prep: x->fp16, W->fp16 (single), mask->valid ----------------
// block ranges: [0,16384) x conv | [16384,19456) Wqkv | [19456,20480) Wout |
// [20480,20544) mask.  Mask dtype detection is CONTENT-based (size ratios
// can't distinguish bool from int32 when sizes are in elements; the wrong
// guess reads 48 KiB OOB).  Scan of first 4096 words is in-bounds for every
// candidate dtype.
// W single-fp16 rationale: absmax stayed pinned at 2^-11 across r0-r8's very
// different pipelines -> error is dominated by the shared Xh/Y fp16
// quantization, not W.  W in (-2^-5, 2^-5) quantizes at rel 2.4e-4, adding
// ~1.4x to the existing qkv error -> predicted final absmax <= 9e-4 vs
// threshold 1.406e-3.  Dropping the hi/lo split halves all GEMM MFMA work.
__global__ __launch_bounds__(256) void prep_k(
    const float* __restrict__ x, _Float16* __restrict__ Xh,
    const float* __restrict__ Wq, _Float16* __restrict__ Wqh,
    const float* __restrict__ Wo, _Float16* __restrict__ Woh,
    const void* __restrict__ mask, float* __restrict__ valid) {
  const int b = blockIdx.x, tid = threadIdx.x;
  if (b < 16384) {                       // x -> fp16, float4 granule
    int i = b * 256 + tid;
    float4 v = ((const float4*)x)[i];
    f16x4 h;
    h[0] = (_Float16)v.x; h[1] = (_Float16)v.y;
    h[2] = (_Float16)v.z; h[3] = (_Float16)v.w;
    ((f16x4*)Xh)[i] = h;
  } else if (b < 19456) {                // W_qkv -> fp16
    int i = (b - 16384) * 256 + tid;
    float4 v = ((const float4*)Wq)[i];
    f16x4 h;
    h[0] = (_Float16)v.x; h[1] = (_Float16)v.y;
    h[2] = (_Float16)v.z; h[3] = (_Float16)v.w;
    ((f16x4*)Wqh)[i] = h;
  } else if (b < 20480) {                // W_out -> fp16
    int i = (b - 19456) * 256 + tid;
    float4 v = ((const float4*)Wo)[i];
    f16x4 h;
    h[0] = (_Float16)v.x; h[1] = (_Float16)v.y;
    h[2] = (_Float16)v.z; h[3] = (_Float16)v.w;
    ((f16x4*)Woh)[i] = h;
  } else {                               // mask -> valid (True = PAD -> 0)
    __shared__ unsigned int sni, snf;
    if (tid == 0) { sni = 0u; snf = 0u; }
    __syncthreads();
    const unsigned int* mw = (const unsigned int*)mask;
    unsigned int ni = 0, nf = 0;
    for (int t = tid; t < 4096; t += 256) {   // 16 KiB: in-bounds all dtypes
      unsigned int v = mw[t];
      ni |= (v > 1u) ? 1u : 0u;
      nf |= (v != 0u && v != 0x3F800000u) ? 1u : 0u;
    }
    if (ni) atomicOr(&sni, 1u);
    if (nf) atomicOr(&snf, 1u);
    __syncthreads();
    const int f = (!sni) ? 0 : ((!snf) ? 1 : 2);
    int i = (b - 20480) * 256 + tid;
    int m;
    if (f == 0)      m = ((const int*)mask)[i] != 0;
    else if (f == 1) m = ((const float*)mask)[i] != 0.0f;
    else             m = ((const unsigned char*)mask)[i] != 0;
    valid[i] = m ? 0.0f : 1.0f;
  }
}

// ---------------- fp16 MFMA GEMM, 256x256 tile, 2-phase pipelined ----------------
// out[m][j] = sum_k A[m][k] * Bh[j][k]   (single-term fp16)
// 8 waves (2M x 4N), per-wave 128x64, K-tile 32, 3-deep LDS staging (96 KiB
// of a 128 KiB block; EPI2 reuses the full 128 KiB as transpose scratch).
// Per K-tile: P1{read a1(cur); stage A(t+2)x2; vmcnt(2) -> tile t+1 resident;
// barrier; 16 mfma a0*bh} P2{preread a0',bh'(nxt); stage Bh(t+2)x2; barrier;
// 16 mfma a1*bh}.  Prereads complete (lgkmcnt before mma) >=1 phase before
// their buffer is restaged, and stage-writes land >=300cy after issue -> no
// read/overwrite race (same margin as the r3/r8 passing schedule).
// XCD swizzle: r3's m-major form (compact 2D patch per XCD).
// EPI 0: qkv epilogue (bias + phi/mask -> [B,H,N,D] fp32)
// EPI 1: bias + row-major fp32 (out-proj)
// EPI 2: fused Q-proj + apply (den via shfl_xor; num via in-LDS C->A-frag
//        transpose, XOR-swizzled, x kvT fp16 hi/lo; 3-term product).

#define TILE_BODY(PC, DO_STAGE, DO_PRE, WAITK, KS)                             \
  {                                                                            \
    const _Float16* bb = lds + (PC) * 16384;                                   \
    const _Float16* nb = lds + (((PC) + 1) % 3) * 16384;                       \
    _Float16* sq = lds + (((PC) + 2) % 3) * 16384;                             \
    const size_t ks = (KS);                                                    \
    /* P1: read a1(cur); stage A(t+2); wait tile t+1 resident; mma a0*bh */    \
    _Pragma("unroll") for (int i = 0; i < 4; ++i)                              \
      a1[i] = *(const f16x8*)&bb[(wm * 8 + 4 + i) * 512 + lane * 8];           \
    if (DO_STAGE) { GLOAD(A + gA0 + ks, sq + w * 512);                         \
                    GLOAD(A + gA1 + ks, sq + 4096 + w * 512); }                \
    if ((WAITK) == 1) { WAITV2(); } else if ((WAITK) == 2) { WAITV0(); }       \
    BARM();                                                                    \
    PRIO1();                                                                   \
    _Pragma("unroll") for (int i = 0; i < 4; ++i)                              \
      _Pragma("unroll") for (int j = 0; j < 4; ++j)                            \
        acc[i][j] = mfma16h(a0[i], bh[j], acc[i][j]);                          \
    PRIO0();                                                                   \
    /* P2: preread a0',bh'(nxt); stage Bh(t+2); mma a1*bh */                   \
    if (DO_PRE) {                                                              \
      _Pragma("unroll") for (int i = 0; i < 4; ++i)                            \
        a0n[i] = *(const f16x8*)&nb[(wm * 8 + i) * 512 + lane * 8];            \
      _Pragma("unroll") for (int j = 0; j < 4; ++j)                            \
        bhn[j] = *(const f16x8*)&nb[8192 + (wj * 4 + j) * 512 + lane * 8];     \
    }                                                                          \
    if (DO_STAGE) { GLOAD(Bh + gB0 + ks, sq + 8192 + w * 512);                 \
                    GLOAD(Bh + gB1 + ks, sq + 12288 + w * 512); }              \
    BARM();                                                                    \
    PRIO1();                                                                   \
    _Pragma("unroll") for (int i = 0; i < 4; ++i)                              \
      _Pragma("unroll") for (int j = 0; j < 4; ++j)                            \
        acc[4 + i][j] = mfma16h(a1[i], bh[j], acc[4 + i][j]);                  \
    PRIO0();                                                                   \
    if (DO_PRE) {                                                              \
      _Pragma("unroll") for (int i = 0; i < 4; ++i) a0[i] = a0n[i];            \
      _Pragma("unroll") for (int j = 0; j < 4; ++j) bh[j] = bhn[j];            \
    }                                                                          \
  }

template <int EPI>
__global__ __launch_bounds__(512, 2) void gemm256_k(
    const _Float16* __restrict__ A, const _Float16* __restrict__ Bh,
    const float* __restrict__ bias, const float* __restrict__ valid,
    float* __restrict__ qf, float* __restrict__ kf, float* __restrict__ vv,
    float* __restrict__ outp, int jb, int jshift,
    const _Float16* __restrict__ kvt_h, const _Float16* __restrict__ kvt_l,
    const float* __restrict__ zv, _Float16* __restrict__ Yo) {
  // staging: 3 bufs x (A 8192 + Bh 8192 halfs) = 96 KiB; EPI2 scratch needs
  // 8 waves x 16 KiB = 128 KiB -> declare 128 KiB (still 1 block/CU).
  __shared__ _Float16 lds[65536];
  const int tid = threadIdx.x;
  const int lane = tid & 63, w = tid >> 6;
  const int lm = lane & 15, lq = lane >> 4;
  const int wm = w >> 2, wj = w & 3;

  // XCD swizzle (bijective; nwg multiple of 8), r3 form: m-major within each
  // XCD's contiguous wid chunk -> compact 2D patch per XCD.
  const int nwg = gridDim.x;
  const int q8 = nwg >> 3;
  const int wid = (blockIdx.x & 7) * q8 + (blockIdx.x >> 3);
  const int j_blk = wid & ((1 << jshift) - 1);
  const int m_blk = wid >> jshift;
  const int m0 = m_blk * 256;
  const int jg0 = jb + j_blk * 256;

  // per-lane global source offsets (halfs); frag f = r*8 + w covers rows f*16+lm
  const size_t gA0 = (size_t)(m0 + w * 16 + lm) * GK + lq * 8;
  const size_t gA1 = gA0 + (size_t)128 * GK;
  const size_t gB0 = (size_t)(jg0 + w * 16 + lm) * GK + lq * 8;
  const size_t gB1 = gB0 + (size_t)128 * GK;

  // ---- prologue: stage tiles 0 (buf0) and 1 (buf1); wait tile0; preread ----
#pragma unroll
  for (int tt = 0; tt < 2; ++tt) {
    _Float16* sq = lds + tt * 16384;
    const size_t ks = (size_t)tt * 32;
    GLOAD(A + gA0 + ks, sq + w * 512);
    GLOAD(A + gA1 + ks, sq + 4096 + w * 512);
    GLOAD(Bh + gB0 + ks, sq + 8192 + w * 512);
    GLOAD(Bh + gB1 + ks, sq + 12288 + w * 512);
  }
  WAITV4();   // 8 outstanding -> oldest 4 (tile 0) complete
  BARM();

  f32x4 acc[8][4] = {};
  f16x8 a0[4], a1[4], bh[4], a0n[4], bhn[4];
#pragma unroll
  for (int i = 0; i < 4; ++i)
    a0[i] = *(const f16x8*)&lds[(wm * 8 + i) * 512 + lane * 8];
#pragma unroll
  for (int j = 0; j < 4; ++j)
    bh[j] = *(const f16x8*)&lds[8192 + (wj * 4 + j) * 512 + lane * 8];

  // ---- main: tiles 0..29 with static buffer indices (10 x 3 unroll) ----
  for (int it = 0; it < 10; ++it) {
    const int t0 = 3 * it;
    TILE_BODY(0, true, true, 1, (size_t)(t0 + 2) * 32)
    TILE_BODY(1, true, true, 1, (size_t)(t0 + 3) * 32)
    TILE_BODY(2, true, true, 1, (size_t)(t0 + 4) * 32)
  }
  // ---- tail: tile 30 (buf 0; drain tile31 stages before preread), tile 31 ----
  TILE_BODY(0, false, true, 2, 0)
  TILE_BODY(1, false, false, 0, 0)

  // C/D layout: col = lane&15, row = (lane>>4)*4 + reg   [m89-verified]
  if (EPI == 0) {
    const int ty = jg0 >> 10;  // 1:k 2:v  (uniform per block)
    float* dst = (ty == 0) ? qf : ((ty == 1) ? kf : vv);
    float vld[8][4];
#pragma unroll
    for (int i = 0; i < 8; ++i)
#pragma unroll
      for (int r = 0; r < 4; ++r)
        vld[i][r] = (ty == 0) ? 1.0f : valid[m0 + wm * 128 + i * 16 + lq * 4 + r];
#pragma unroll
    for (int jt = 0; jt < 4; ++jt) {
      int jcol = jg0 + wj * 64 + jt * 16 + lm;
      float bj = bias[jcol];
      int c = jcol & 1023, hd = c >> 6, d = c & 63;
#pragma unroll
      for (int i = 0; i < 8; ++i)
#pragma unroll
        for (int r = 0; r < 4; ++r) {
          int m = m0 + wm * 128 + i * 16 + lq * 4 + r;
          int b = m >> 12, n = m & 4095;
          float val = acc[i][jt][r] + bj;
          if (ty <= 1) val = phi_f(val);
          if (ty >= 1) val *= vld[i][r];
          dst[(((size_t)(b * H_ + hd) * N_ + n) << 6) + d] = val;
        }
    }
  } else if (EPI == 1) {
#pragma unroll
    for (int jt = 0; jt < 4; ++jt) {
      int jcol = jg0 + wj * 64 + jt * 16 + lm;
      float bj = bias[jcol];
#pragma unroll
      for (int i = 0; i < 8; ++i)
#pragma unroll
        for (int r = 0; r < 4; ++r) {
          int m = m0 + wm * 128 + i * 16 + lq * 4 + r;
          outp[(size_t)m * C_ + jcol] = acc[i][jt][r] + bj;
        }
    }
  } else {
    // ---- EPI 2: fused Q-projection + apply ----
    const int head = (jg0 >> 6) + wj;          // j_blk*4 + wj
    const int bidx = m0 >> 12;                 // one batch per 256-row block
    const int bh_idx = bidx * H_ + head;
    const size_t kvbase = (size_t)bh_idx * 4096;
    // 1. val = phi(q + bias) in place; den = 1/max(qf.z, eps) per row
    float breg[4], zreg[4];
#pragma unroll
    for (int jt = 0; jt < 4; ++jt) {
      breg[jt] = bias[jg0 + wj * 64 + jt * 16 + lm];
      zreg[jt] = zv[bh_idx * 64 + jt * 16 + lm];
    }
    float den[8][4];
#pragma unroll
    for (int i = 0; i < 8; ++i)
#pragma unroll
      for (int r = 0; r < 4; ++r) {
        float p = 0.f;
#pragma unroll
        for (int jt = 0; jt < 4; ++jt) {
          float v = phi_f(acc[i][jt][r] + breg[jt]);
          acc[i][jt][r] = v;
          p += v * zreg[jt];
        }
        p += __shfl_xor(p, 1); p += __shfl_xor(p, 2);
        p += __shfl_xor(p, 4); p += __shfl_xor(p, 8);
        den[i][r] = 1.0f / fmaxf(p, 1e-6f);
      }
    // 2. all waves done with K-loop LDS -> safe to reuse as transpose scratch
    BARM();
    char* sb = (char*)(lds) + w * 16384;       // 16 KiB private slice per wave
    // 3. two row-halves: transpose C-frags -> A-frags (hi/lo fp16), PV MFMA
#pragma unroll
    for (int h = 0; h < 2; ++h) {
#pragma unroll
      for (int i2 = 0; i2 < 4; ++i2) {
#pragma unroll
        for (int jt = 0; jt < 4; ++jt)
#pragma unroll
          for (int r = 0; r < 4; ++r) {
            int row = i2 * 16 + lq * 4 + r;    // 0..63 within half
            int d = jt * 16 + lm;
            float v = acc[h * 4 + i2][jt][r];
            _Float16 vh = (_Float16)v;
            _Float16 vl = (_Float16)(v - (float)vh);
            int bo = (row * 128 + d * 2) ^ ((row & 7) << 4);  // G4 swizzle
            *(_Float16*)(sb + bo) = vh;
            *(_Float16*)(sb + 8192 + bo) = vl;
          }
      }
      WAITL0(); SCHEDB();                      // writes land before reads
      f32x4 acc2[4][4] = {};
#pragma unroll
      for (int ks = 0; ks < 2; ++ks) {
        f16x8 ah[4], al[4], bhf[4], blf[4];
#pragma unroll
        for (int f = 0; f < 4; ++f) {
          int row = f * 16 + lm;
          int bo = (row * 128 + ks * 64 + lq * 16) ^ ((row & 7) << 4);
          ah[f] = *(const f16x8*)(sb + bo);
          al[f] = *(const f16x8*)(sb + 8192 + bo);
        }
#pragma unroll
        for (int et = 0; et < 4; ++et) {
          size_t go = kvbase + (size_t)(et * 16 + lm) * 64 + ks * 32 + lq * 8;
          bhf[et] = *(const f16x8*)&kvt_h[go];
          blf[et] = *(const f16x8*)&kvt_l[go];
        }
#pragma unroll
        for (int f = 0; f < 4; ++f)
#pragma unroll
          for (int et = 0; et < 4; ++et) {
            acc2[f][et] = mfma16h(ah[f], bhf[et], acc2[f][et]);
            acc2[f][et] = mfma16h(ah[f], blf[et], acc2[f][et]);
            acc2[f][et] = mfma16h(al[f], bhf[et], acc2[f][et]);
          }
      }
      // 4. y = num * (1/den), fp16, direct to Y
#pragma unroll
      for (int f = 0; f < 4; ++f)
#pragma unroll
        for (int et = 0; et < 4; ++et)
#pragma unroll
          for (int r = 0; r < 4; ++r) {
            int m = m0 + wm * 128 + h * 64 + f * 16 + lq * 4 + r;
            float yv = acc2[f][et][r] * den[h * 4 + f][r];
            Yo[(size_t)m * C_ + head * 64 + et * 16 + lm] = (_Float16)yv;
          }
      WAITL0(); SCHEDB();                      // half1 reads done before half2 writes
    }
  }
}

// ---------------- kv partials: kv[bh][d][e] = sum_n kf[bh][n][d]*v[bh][n][e]; z[bh][d] ----------------
__global__ __launch_bounds__(256) void kv_partial_k(
    const float* __restrict__ kf, const float* __restrict__ vv,
    float* __restrict__ kvp, float* __restrict__ zp) {
  const int bh = blockIdx.x, ch = blockIdx.y;
  const float* kfr = kf + ((size_t)bh * N_ + ch * CHROWS) * 64;
  const float* vr  = vv + ((size_t)bh * N_ + ch * CHROWS) * 64;
  __shared__ float vs[16][64];
  const int tid = threadIdx.x;
  const int d4 = tid >> 4, e4 = tid & 15;
  const int srow = tid >> 4, scol = (tid & 15) * 4;
  float acc[4][4] = {};
  float zacc[4] = {};
  for (int nb = 0; nb < CHROWS; nb += 16) {
    float4 st = *(const float4*)&vr[(size_t)(nb + srow) * 64 + scol];
    __syncthreads();                       // prev round's reads done
    *(float4*)&vs[srow][scol] = st;
    float4 kq[16];
#pragma unroll
    for (int r = 0; r < 16; ++r)
      kq[r] = *(const float4*)&kfr[(size_t)(nb + r) * 64 + d4 * 4];
    __syncthreads();                       // vs visible
#pragma unroll
    for (int r = 0; r < 16; ++r) {
      float4 vq = *(const float4*)&vs[r][e4 * 4];
      float kk[4] = {kq[r].x, kq[r].y, kq[r].z, kq[r].w};
      float vk[4] = {vq.x, vq.y, vq.z, vq.w};
#pragma unroll
      for (int di = 0; di < 4; ++di) {
        if (e4 == 0) zacc[di] += kk[di];
#pragma unroll
        for (int ei = 0; ei < 4; ++ei) acc[di][ei] += kk[di] * vk[ei];
      }
    }
  }
  size_t base = ((size_t)bh * NCH + ch) * 4096 + (size_t)d4 * 4 * 64 + e4 * 4;
#pragma unroll
  for (int di = 0; di < 4; ++di)
    *(float4*)&kvp[base + (size_t)di * 64] =
        make_float4(acc[di][0], acc[di][1], acc[di][2], acc[di][3]);
  if (e4 == 0)
    *(float4*)&zp[((size_t)bh * NCH + ch) * 64 + d4 * 4] =
        make_float4(zacc[0], zacc[1], zacc[2], zacc[3]);
}

// reduce partials -> kvT (fp16 hi/lo, [bh][e][d] -- B-fragment-ready) + z fp32
__global__ __launch_bounds__(256) void kv_reduce_k(
    const float* __restrict__ kvp, const float* __restrict__ zp,
    _Float16* __restrict__ kvt_h, _Float16* __restrict__ kvt_l,
    float* __restrict__ z) {
  const int bh = blockIdx.x, tid = threadIdx.x;
  for (int i = tid; i < 4096; i += 256) {
    float s = 0.f;
#pragma unroll
    for (int c = 0; c < NCH; ++c) s += kvp[((size_t)bh * NCH + c) * 4096 + i];
    int d = i >> 6, e = i & 63;
    _Float16 sh = (_Float16)s;
    kvt_h[(size_t)bh * 4096 + e * 64 + d] = sh;
    kvt_l[(size_t)bh * 4096 + e * 64 + d] = (_Float16)(s - (float)sh);
  }
  if (tid < 64) {
    float s = 0.f;
#pragma unroll
    for (int c = 0; c < NCH; ++c) s += zp[((size_t)bh * NCH + c) * 64 + tid];
    z[bh * 64 + tid] = s;
  }
}

extern "C" void kernel_launch(void* const* d_in, const int* in_sizes, int n_in,
                              void* d_out, int out_size, void* d_ws, size_t ws_size,
                              hipStream_t stream) {
  const float* x      = (const float*)d_in[0];
  const float* W_qkv  = (const float*)d_in[1];
  const float* b_qkv  = (const float*)d_in[2];
  const float* W_out  = (const float*)d_in[3];
  const float* b_out  = (const float*)d_in[4];
  const void*  mask   = d_in[5];
  float* out = (float*)d_out;

  const size_t bhnd = (size_t)B_ * H_ * N_ * D_;   // 16,777,216
  float* ws = (float*)d_ws;
  float* buf1 = ws;                    // kf (fp32)
  float* buf2 = ws + bhnd;             // v (fp32), then Y (fp16)
  _Float16* Xh  = (_Float16*)(ws + 2 * bhnd);      // bhnd halfs
  _Float16* Wqh = Xh + bhnd;                       // 3072*1024
  _Float16* Woh = Wqh + (size_t)3072 * 1024;       // 1024*1024
  float* tail2 = (float*)(Woh + (size_t)1024 * 1024);
  float* kvp = tail2;                              // 64*8*4096
  float* zp  = kvp + (size_t)64 * NCH * 4096;
  float* z   = zp + (size_t)64 * NCH * 64;
  float* valid = z + 64 * 64;
  _Float16* kvt_h = (_Float16*)(valid + M_);       // 64*4096 halfs
  _Float16* kvt_l = kvt_h + (size_t)64 * 4096;

  _Float16* Y = (_Float16*)buf2;

  // fused prep: x conv + W convs + mask->valid (1 dispatch, 20544 blocks)
  prep_k<<<20544, 256, 0, stream>>>(x, Xh, W_qkv, Wqh, W_out, Woh, mask, valid);
  // phase A: K and V projections (j in [1024,3072)) -> kf(buf1), v(buf2)
  gemm256_k<0><<<512, 512, 0, stream>>>(
      Xh, Wqh, b_qkv, valid, buf1, buf1, buf2, nullptr, 1024, 3,
      nullptr, nullptr, nullptr, nullptr);
  kv_partial_k<<<dim3(B_ * H_, NCH), 256, 0, stream>>>(buf1, buf2, kvp, zp);
  kv_reduce_k<<<B_ * H_, 256, 0, stream>>>(kvp, zp, kvt_h, kvt_l, z);
  // phase B: fused Q projection + apply -> Y (fp16) into buf2 (v dead)
  gemm256_k<2><<<256, 512, 0, stream>>>(
      Xh, Wqh, b_qkv, valid, nullptr, nullptr, nullptr, nullptr, 0, 2,
      kvt_h, kvt_l, z, Y);
  // out-proj: A = Y (fp16), B = W_out (fp16)
  gemm256_k<1><<<256, 512, 0, stream>>>(
      Y, Woh, b_out, valid, nullptr, nullptr, nullptr, out, 0, 2,
      nullptr, nullptr, nullptr, nullptr);
}